// Round 1
// baseline (44799.707 us; speedup 1.0000x reference)
//
#include <hip/hip_runtime.h>
#include <cstdint>
#include <cstddef>

#define B_  32
#define S_  512
#define I_  256
#define H_  1024
#define O_  256
#define H3  3072
#define M_  16384   // S_*B_
#define OUT_OFF 4194304  // B*S*O

typedef __attribute__((ext_vector_type(8))) short  short8;
typedef __attribute__((ext_vector_type(4))) float  f32x4;
typedef __attribute__((ext_vector_type(4))) unsigned short us4;
typedef __attribute__((ext_vector_type(2))) unsigned short us2;
typedef __attribute__((ext_vector_type(4))) unsigned int   u32x4;

// ---- workspace layout (bytes) ----
static const size_t XP_OFF    = 0;                          // bf16 [S][3H][B]  100,663,296
static const size_t SEQT_OFF  = 100663296;                  // f32 [(S+1)][H][B] 67,239,936
static const size_t XBF_OFF   = 167903232;                  // bf16 [M][1024]    33,554,432
static const size_t WHBF_OFF  = 201457664;                  // bf16 3*[3H][H]    18,874,368
static const size_t WX0_OFF   = 220332032;                  // bf16 [3H][256]     1,572,864
static const size_t WX12_OFF  = 221904896;                  // bf16 2*[3H][H]    12,582,912
static const size_t WOUT_OFF  = 234487808;                  // bf16 [O][H]          524,288
static const size_t ZBUF_OFF  = 235012096;                  // f32 [H][B]           131,072
static const size_t RH_OFF    = 235143168;                  // f32 [H][B]           131,072
static const size_t FLAG_OFF  = 235274240;                  // 4096
static const size_t WS_NEED   = 235278336;

__device__ inline unsigned short f2bf(float f){
  unsigned u = __builtin_bit_cast(unsigned, f);
  unsigned r = u + 0x7fffu + ((u >> 16) & 1u);
  return (unsigned short)(r >> 16);
}
__device__ inline float bf2f(unsigned short s){
  unsigned u = ((unsigned)s) << 16;
  return __builtin_bit_cast(float, u);
}

// ---------------- simple converts ----------------
__global__ void k_conv(const float* __restrict__ src, unsigned short* __restrict__ dst, int n){
  int i = blockIdx.x*256 + threadIdx.x;
  if (i < n) dst[i] = f2bf(src[i]);
}

// x [B][S][I] fp32 -> xbf rows (s*32+b) x 256 bf16
__global__ void k_convx(const float* __restrict__ x, unsigned short* __restrict__ xbf){
  int row = blockIdx.x;          // s*32+b
  int s = row >> 5, b = row & 31;
  int i = threadIdx.x;           // 0..255
  xbf[(size_t)row*I_ + i] = f2bf(x[((size_t)b*S_ + s)*I_ + i]);
}

// seqT[0][hh][b] = h0[b][l][hh]
__global__ void k_seth0(const float* __restrict__ h0, float* __restrict__ seqT, int l){
  int i = blockIdx.x*256 + threadIdx.x;   // 0..32767 = hh*32+b
  int hh = i >> 5, b = i & 31;
  seqT[i] = h0[((size_t)b*3 + l)*H_ + hh];
}

// d_out hidden part: out[b][l][hh] = seqT[512][hh][b]
__global__ void k_final(const float* __restrict__ seqT, float* __restrict__ out, int l){
  int i = blockIdx.x*256 + threadIdx.x;   // hh*32+b
  int hh = i >> 5, b = i & 31;
  out[(size_t)OUT_OFF + ((size_t)b*3 + l)*H_ + hh] = seqT[(size_t)512*32768 + i];
}

// seqT[s+1][h][b] f32 -> xbf[(s*32+b)][h] bf16   (tiled transpose)
__global__ void k_transp(const float* __restrict__ seqT, unsigned short* __restrict__ xbf){
  __shared__ float tile[64][33];
  int s = blockIdx.x, hc = blockIdx.y;
  int x = threadIdx.x & 31;   // b on read
  int y = threadIdx.x >> 5;   // 0..7
  const float* src = seqT + ((size_t)(s+1)*H_ + hc*64)*32;
  #pragma unroll
  for (int k = 0; k < 8; k++) tile[y*8 + k][x] = src[(size_t)(y*8 + k)*32 + x];
  __syncthreads();
  #pragma unroll
  for (int bb = 0; bb < 4; bb++){
    int b = bb*8 + y;
    size_t row = ((size_t)s*32 + b)*H_ + (size_t)hc*64;
    us2 v;
    v.x = f2bf(tile[x*2][b]);
    v.y = f2bf(tile[x*2+1][b]);
    *(us2*)(xbf + row + x*2) = v;
  }
}

// ---------------- bf16 MFMA GEMM: C = A * Bw^T + bias ----------------
// A: bf16 [M_][Kd] (row = logical m for mode0, remapped for mode1)
// Bw: bf16 [Nd][Kd] row-major
// mode0: Cout = xp bf16 at [s][n][b] (m = s*32+b), bias fp32[n]
// mode1: Cout = fp32 at m*Nd + n (m = b*512+s, A row phys = (m&511)*32+(m>>9))
__global__ __launch_bounds__(256) void k_gemm(const unsigned short* __restrict__ A,
                                              const unsigned short* __restrict__ Bw,
                                              const float* __restrict__ bias,
                                              void* __restrict__ Cout,
                                              int Kd, int mode, int Nd){
  __shared__ __align__(16) unsigned short lA[128*40];
  __shared__ __align__(16) unsigned short lB[128*40];
  int bm = blockIdx.y * 128, bn = blockIdx.x * 128;
  int tid = threadIdx.x;
  int w = tid >> 6, lane = tid & 63, q = lane >> 4, cc = lane & 15;
  int wm = (w >> 1) * 64, wn = (w & 1) * 64;
  f32x4 acc[4][4] = {};
  for (int k0 = 0; k0 < Kd; k0 += 32){
    #pragma unroll
    for (int i = 0; i < 2; i++){
      int idx = tid + i*256;          // 0..511
      int r = idx >> 2, ch = idx & 3;
      int m = bm + r;
      int arow = (mode == 0) ? m : ((m & 511)*32 + (m >> 9));
      *(u32x4*)(lA + r*40 + ch*8) = *(const u32x4*)(A + (size_t)arow*Kd + k0 + ch*8);
      *(u32x4*)(lB + r*40 + ch*8) = *(const u32x4*)(Bw + (size_t)(bn + r)*Kd + k0 + ch*8);
    }
    __syncthreads();
    short8 af[4], bfv[4];
    #pragma unroll
    for (int i = 0; i < 4; i++) af[i]  = *(const short8*)(lA + (wm + i*16 + cc)*40 + q*8);
    #pragma unroll
    for (int i = 0; i < 4; i++) bfv[i] = *(const short8*)(lB + (wn + i*16 + cc)*40 + q*8);
    #pragma unroll
    for (int i = 0; i < 4; i++)
      #pragma unroll
      for (int j = 0; j < 4; j++)
        acc[i][j] = __builtin_amdgcn_mfma_f32_16x16x32_bf16(af[i], bfv[j], acc[i][j], 0, 0, 0);
    __syncthreads();
  }
  if (mode == 0){
    unsigned short* xp = (unsigned short*)Cout;
    #pragma unroll
    for (int i = 0; i < 4; i++){
      #pragma unroll
      for (int j = 0; j < 4; j++){
        int m = bm + wm + i*16 + q*4;
        int n = bn + wn + j*16 + cc;
        float bv = bias[n];
        int s = m >> 5, b0 = m & 31;
        us4 pk;
        #pragma unroll
        for (int reg = 0; reg < 4; reg++) pk[reg] = f2bf(acc[i][j][reg] + bv);
        *(us4*)(xp + ((size_t)s*H3 + n)*32 + b0) = pk;
      }
    }
  } else {
    float* C = (float*)Cout;
    #pragma unroll
    for (int i = 0; i < 4; i++){
      #pragma unroll
      for (int j = 0; j < 4; j++){
        int m = bm + wm + i*16 + q*4;
        int n = bn + wn + j*16 + cc;
        float bv = bias[n];
        #pragma unroll
        for (int reg = 0; reg < 4; reg++)
          C[(size_t)(m + reg)*Nd + n] = acc[i][j][reg] + bv;
      }
    }
  }
}

// ---------------- persistent recurrence ----------------
// grid = 128 blocks x 256 threads, all co-resident
__device__ inline void gbar(unsigned* flags, unsigned ep){
  __syncthreads();
  if (threadIdx.x == 0)
    __hip_atomic_store(flags + blockIdx.x, ep, __ATOMIC_RELEASE, __HIP_MEMORY_SCOPE_AGENT);
  if (threadIdx.x < 128){
    while (__hip_atomic_load(flags + threadIdx.x, __ATOMIC_ACQUIRE, __HIP_MEMORY_SCOPE_AGENT) < ep){
      __builtin_amdgcn_s_sleep(1);
    }
  }
  __syncthreads();
}

__global__ __launch_bounds__(256) void k_rec(float* __restrict__ seqT,
                                             const unsigned short* __restrict__ xp,
                                             const unsigned short* __restrict__ wh,
                                             float* __restrict__ zbuf,
                                             float* __restrict__ rhbuf,
                                             unsigned* flags){
  __shared__ float red[1536];
  int tid = threadIdx.x, w = tid >> 6, lane = tid & 63, q = lane >> 4, c = lane & 15;
  int blk = blockIdx.x;
  unsigned ep = 1;
  for (int t = 0; t < S_; t++){
    const float* ht = seqT + (size_t)t * 32768;
    // ---- phase A: z,r matvec (rows 0..2047), K split 4 ways across waves ----
    {
      int n0 = blk * 16;
      f32x4 acc0 = {0,0,0,0}, acc1 = {0,0,0,0};
      const unsigned short* wrow = wh + (size_t)(n0 + c)*H_ + w*256 + q*8;
      const float* hbase = ht + (size_t)(w*256 + q*8)*32;
      #pragma unroll
      for (int i = 0; i < 8; i++){
        short8 bfrg = *(const short8*)(wrow + i*32);
        const float* hp = hbase + (size_t)i*32*32;
        short8 a0, a1;
        #pragma unroll
        for (int j = 0; j < 8; j++){
          a0[j] = (short)f2bf(hp[j*32 + c]);
          a1[j] = (short)f2bf(hp[j*32 + c + 16]);
        }
        acc0 = __builtin_amdgcn_mfma_f32_16x16x32_bf16(a0, bfrg, acc0, 0, 0, 0);
        acc1 = __builtin_amdgcn_mfma_f32_16x16x32_bf16(a1, bfrg, acc1, 0, 0, 0);
      }
      if (w > 0){
        #pragma unroll
        for (int i = 0; i < 4; i++){
          red[(w-1)*512 + lane*8 + i]     = acc0[i];
          red[(w-1)*512 + lane*8 + 4 + i] = acc1[i];
        }
      }
      __syncthreads();
      if (w == 0){
        #pragma unroll
        for (int r = 0; r < 3; r++)
          #pragma unroll
          for (int i = 0; i < 4; i++){
            acc0[i] += red[r*512 + lane*8 + i];
            acc1[i] += red[r*512 + lane*8 + 4 + i];
          }
        int gr = n0 + c;                       // global row (z:0..1023, r:1024..2047)
        const unsigned short* xpp = xp + ((size_t)t*H3 + gr)*32;
        #pragma unroll
        for (int mt = 0; mt < 2; mt++){
          #pragma unroll
          for (int reg = 0; reg < 4; reg++){
            int b = mt*16 + q*4 + reg;
            float pre = (mt ? acc1[reg] : acc0[reg]) + bf2f(xpp[b]);
            float sg = 1.0f / (1.0f + __expf(-pre));
            if (blk < 64){
              zbuf[gr*32 + b] = sg;
            } else {
              int hh = gr - 1024;
              rhbuf[hh*32 + b] = sg * ht[hh*32 + b];
            }
          }
        }
      }
    }
    gbar(flags, ep++);
    // ---- phase B: g matvec on (r.h), rows 2048..3071, then h update ----
    {
      int nt = blk >> 1, mt = blk & 1;
      int n0 = nt * 16;
      f32x4 acc = {0,0,0,0};
      const unsigned short* wrow = wh + (size_t)(2048 + n0 + c)*H_ + w*256 + q*8;
      const float* abase = rhbuf + (size_t)(w*256 + q*8)*32;
      #pragma unroll
      for (int i = 0; i < 8; i++){
        short8 bfrg = *(const short8*)(wrow + i*32);
        const float* ap = abase + (size_t)i*32*32;
        short8 a0;
        #pragma unroll
        for (int j = 0; j < 8; j++) a0[j] = (short)f2bf(ap[j*32 + c + mt*16]);
        acc = __builtin_amdgcn_mfma_f32_16x16x32_bf16(a0, bfrg, acc, 0, 0, 0);
      }
      if (w > 0){
        #pragma unroll
        for (int i = 0; i < 4; i++) red[(w-1)*512 + lane*8 + i] = acc[i];
      }
      __syncthreads();
      if (w == 0){
        #pragma unroll
        for (int r = 0; r < 3; r++)
          #pragma unroll
          for (int i = 0; i < 4; i++) acc[i] += red[r*512 + lane*8 + i];
        int n = n0 + c;
        const unsigned short* xpp = xp + ((size_t)t*H3 + 2048 + n)*32;
        float* hn = seqT + (size_t)(t+1)*32768;
        #pragma unroll
        for (int reg = 0; reg < 4; reg++){
          int b = mt*16 + q*4 + reg;
          float pre = acc[reg] + bf2f(xpp[b]);
          float g = tanhf(pre);
          float z = zbuf[n*32 + b];
          float h = ht[n*32 + b];
          hn[n*32 + b] = z*h + (1.0f - z)*g;
        }
      }
    }
    gbar(flags, ep++);
  }
}

extern "C" void kernel_launch(void* const* d_in, const int* in_sizes, int n_in,
                              void* d_out, int out_size, void* d_ws, size_t ws_size,
                              hipStream_t stream){
  (void)in_sizes; (void)n_in; (void)out_size;
  if (ws_size < WS_NEED) return;

  const float* x    = (const float*)d_in[0];
  const float* h0   = (const float*)d_in[1];
  const float* Wx0  = (const float*)d_in[2];
  const float* Wh0  = (const float*)d_in[3];
  const float* bh0  = (const float*)d_in[4];
  const float* Wx   = (const float*)d_in[5];
  const float* Wh   = (const float*)d_in[6];
  const float* bh   = (const float*)d_in[7];
  const float* Wout = (const float*)d_in[8];
  const float* bout = (const float*)d_in[9];
  float* out = (float*)d_out;

  char* ws = (char*)d_ws;
  unsigned short* xp    = (unsigned short*)(ws + XP_OFF);
  float*          seqT  = (float*)(ws + SEQT_OFF);
  unsigned short* xbf   = (unsigned short*)(ws + XBF_OFF);
  unsigned short* whbf  = (unsigned short*)(ws + WHBF_OFF);
  unsigned short* wx0b  = (unsigned short*)(ws + WX0_OFF);
  unsigned short* wx12b = (unsigned short*)(ws + WX12_OFF);
  unsigned short* woutb = (unsigned short*)(ws + WOUT_OFF);
  float*          zbuf  = (float*)(ws + ZBUF_OFF);
  float*          rhbuf = (float*)(ws + RH_OFF);
  unsigned*       flags = (unsigned*)(ws + FLAG_OFF);

  hipMemsetAsync(ws + FLAG_OFF, 0, 4096, stream);

  k_conv<<<(3145728+255)/256, 256, 0, stream>>>(Wh0, whbf, 3145728);
  k_conv<<<(6291456+255)/256, 256, 0, stream>>>(Wh,  whbf + 3145728, 6291456);
  k_conv<<<(786432+255)/256,  256, 0, stream>>>(Wx0, wx0b, 786432);
  k_conv<<<(6291456+255)/256, 256, 0, stream>>>(Wx,  wx12b, 6291456);
  k_conv<<<(262144+255)/256,  256, 0, stream>>>(Wout, woutb, 262144);
  k_convx<<<16384, 256, 0, stream>>>(x, xbf);

  for (int l = 0; l < 3; l++){
    k_seth0<<<128, 256, 0, stream>>>(h0, seqT, l);
    const unsigned short* wxl = (l == 0) ? wx0b : (wx12b + (size_t)(l-1)*3145728);
    const float* biasl = (l == 0) ? bh0 : (bh + (size_t)(l-1)*3072);
    int Kd = (l == 0) ? 256 : 1024;
    dim3 g(24, 128);
    k_gemm<<<g, 256, 0, stream>>>(xbf, wxl, biasl, (void*)xp, Kd, 0, H3);
    k_rec<<<128, 256, 0, stream>>>(seqT, xp, whbf + (size_t)l*3145728, zbuf, rhbuf, flags + (size_t)l*128);
    k_final<<<128, 256, 0, stream>>>(seqT, out, l);
    k_transp<<<dim3(512, 16), 256, 0, stream>>>(seqT, xbf);
  }
  dim3 g2(2, 128);
  k_gemm<<<g2, 256, 0, stream>>>(xbf, woutb, bout, (void*)out, 1024, 1, 256);
}

// Round 2
// 21807.587 us; speedup vs baseline: 2.0543x; 2.0543x over previous
//
#include <hip/hip_runtime.h>
#include <cstdint>
#include <cstddef>

#define B_  32
#define S_  512
#define I_  256
#define H_  1024
#define O_  256
#define H3  3072
#define M_  16384   // S_*B_
#define OUT_OFF 4194304  // B*S*O

typedef __attribute__((ext_vector_type(8))) short  short8;
typedef __attribute__((ext_vector_type(4))) float  f32x4;
typedef __attribute__((ext_vector_type(4))) unsigned short us4;
typedef __attribute__((ext_vector_type(2))) unsigned short us2;
typedef __attribute__((ext_vector_type(4))) unsigned int   u32x4;

// ---- workspace layout (bytes) ----
static const size_t XP_OFF    = 0;                          // bf16 [S][3H][B]  100,663,296
static const size_t SEQT_OFF  = 100663296;                  // f32 [(S+1)][H][B] 67,239,936
static const size_t XBF_OFF   = 167903232;                  // bf16 [M][1024]    33,554,432
static const size_t WHBF_OFF  = 201457664;                  // bf16 3*[3H][H]    18,874,368
static const size_t WX0_OFF   = 220332032;                  // bf16 [3H][256]     1,572,864
static const size_t WX12_OFF  = 221904896;                  // bf16 2*[3H][H]    12,582,912
static const size_t WOUT_OFF  = 234487808;                  // bf16 [O][H]          524,288
static const size_t ZBUF_OFF  = 235012096;                  // f32 bits [H][B]      131,072
static const size_t RHB_OFF   = 235143168;                  // uint [H/2][B]         65,536
static const size_t HB_OFF    = 235208704;                  // uint [H/2][B]         65,536
static const size_t FLAG_OFF  = 235274240;                  // 4096
static const size_t WS_NEED   = 235278336;

__device__ inline unsigned short f2bf(float f){
  unsigned u = __builtin_bit_cast(unsigned, f);
  unsigned r = u + 0x7fffu + ((u >> 16) & 1u);
  return (unsigned short)(r >> 16);
}
__device__ inline float bf2f(unsigned short s){
  unsigned u = ((unsigned)s) << 16;
  return __builtin_bit_cast(float, u);
}

// bypass (IF coherence point) ops: relaxed system-scope -> sc0 sc1, no cache flush
__device__ inline unsigned ld_sys(const unsigned* p){
  return __hip_atomic_load(p, __ATOMIC_RELAXED, __HIP_MEMORY_SCOPE_SYSTEM);
}
__device__ inline void st_sys(unsigned* p, unsigned v){
  __hip_atomic_store(p, v, __ATOMIC_RELAXED, __HIP_MEMORY_SCOPE_SYSTEM);
}

// ---------------- simple converts ----------------
__global__ void k_conv(const float* __restrict__ src, unsigned short* __restrict__ dst, int n){
  int i = blockIdx.x*256 + threadIdx.x;
  if (i < n) dst[i] = f2bf(src[i]);
}

// x [B][S][I] fp32 -> xbf rows (s*32+b) x 256 bf16
__global__ void k_convx(const float* __restrict__ x, unsigned short* __restrict__ xbf){
  int row = blockIdx.x;          // s*32+b
  int s = row >> 5, b = row & 31;
  int i = threadIdx.x;           // 0..255
  xbf[(size_t)row*I_ + i] = f2bf(x[((size_t)b*S_ + s)*I_ + i]);
}

// seqT[0][hh][b] = h0[b][l][hh]; also packed bf16 hb
__global__ void k_seth0(const float* __restrict__ h0, float* __restrict__ seqT,
                        unsigned* __restrict__ hb, int l){
  int i = blockIdx.x*256 + threadIdx.x;   // 0..32767 = hh*32+b
  int hh = i >> 5, b = i & 31;
  float v = h0[((size_t)b*3 + l)*H_ + hh];
  seqT[i] = v;
  if (!(hh & 1)){
    float v2 = h0[((size_t)b*3 + l)*H_ + hh + 1];
    hb[(hh >> 1)*32 + b] = (unsigned)f2bf(v) | ((unsigned)f2bf(v2) << 16);
  }
}

// d_out hidden part: out[b][l][hh] = seqT[512][hh][b]
__global__ void k_final(const float* __restrict__ seqT, float* __restrict__ out, int l){
  int i = blockIdx.x*256 + threadIdx.x;   // hh*32+b
  int hh = i >> 5, b = i & 31;
  out[(size_t)OUT_OFF + ((size_t)b*3 + l)*H_ + hh] = seqT[(size_t)512*32768 + i];
}

// seqT[s+1][h][b] f32 -> xbf[(s*32+b)][h] bf16   (tiled transpose)
__global__ void k_transp(const float* __restrict__ seqT, unsigned short* __restrict__ xbf){
  __shared__ float tile[64][33];
  int s = blockIdx.x, hc = blockIdx.y;
  int x = threadIdx.x & 31;   // b on read
  int y = threadIdx.x >> 5;   // 0..7
  const float* src = seqT + ((size_t)(s+1)*H_ + hc*64)*32;
  #pragma unroll
  for (int k = 0; k < 8; k++) tile[y*8 + k][x] = src[(size_t)(y*8 + k)*32 + x];
  __syncthreads();
  #pragma unroll
  for (int bb = 0; bb < 4; bb++){
    int b = bb*8 + y;
    size_t row = ((size_t)s*32 + b)*H_ + (size_t)hc*64;
    us2 v;
    v.x = f2bf(tile[x*2][b]);
    v.y = f2bf(tile[x*2+1][b]);
    *(us2*)(xbf + row + x*2) = v;
  }
}

// ---------------- bf16 MFMA GEMM: C = A * Bw^T + bias ----------------
__global__ __launch_bounds__(256) void k_gemm(const unsigned short* __restrict__ A,
                                              const unsigned short* __restrict__ Bw,
                                              const float* __restrict__ bias,
                                              void* __restrict__ Cout,
                                              int Kd, int mode, int Nd){
  __shared__ __align__(16) unsigned short lA[128*40];
  __shared__ __align__(16) unsigned short lB[128*40];
  int bm = blockIdx.y * 128, bn = blockIdx.x * 128;
  int tid = threadIdx.x;
  int w = tid >> 6, lane = tid & 63, q = lane >> 4, cc = lane & 15;
  int wm = (w >> 1) * 64, wn = (w & 1) * 64;
  f32x4 acc[4][4] = {};
  for (int k0 = 0; k0 < Kd; k0 += 32){
    #pragma unroll
    for (int i = 0; i < 2; i++){
      int idx = tid + i*256;          // 0..511
      int r = idx >> 2, ch = idx & 3;
      int m = bm + r;
      int arow = (mode == 0) ? m : ((m & 511)*32 + (m >> 9));
      *(u32x4*)(lA + r*40 + ch*8) = *(const u32x4*)(A + (size_t)arow*Kd + k0 + ch*8);
      *(u32x4*)(lB + r*40 + ch*8) = *(const u32x4*)(Bw + (size_t)(bn + r)*Kd + k0 + ch*8);
    }
    __syncthreads();
    short8 af[4], bfv[4];
    #pragma unroll
    for (int i = 0; i < 4; i++) af[i]  = *(const short8*)(lA + (wm + i*16 + cc)*40 + q*8);
    #pragma unroll
    for (int i = 0; i < 4; i++) bfv[i] = *(const short8*)(lB + (wn + i*16 + cc)*40 + q*8);
    #pragma unroll
    for (int i = 0; i < 4; i++)
      #pragma unroll
      for (int j = 0; j < 4; j++)
        acc[i][j] = __builtin_amdgcn_mfma_f32_16x16x32_bf16(af[i], bfv[j], acc[i][j], 0, 0, 0);
    __syncthreads();
  }
  if (mode == 0){
    unsigned short* xp = (unsigned short*)Cout;
    #pragma unroll
    for (int i = 0; i < 4; i++){
      #pragma unroll
      for (int j = 0; j < 4; j++){
        int m = bm + wm + i*16 + q*4;
        int n = bn + wn + j*16 + cc;
        float bv = bias[n];
        int s = m >> 5, b0 = m & 31;
        us4 pk;
        #pragma unroll
        for (int reg = 0; reg < 4; reg++) pk[reg] = f2bf(acc[i][j][reg] + bv);
        *(us4*)(xp + ((size_t)s*H3 + n)*32 + b0) = pk;
      }
    }
  } else {
    float* C = (float*)Cout;
    #pragma unroll
    for (int i = 0; i < 4; i++){
      #pragma unroll
      for (int j = 0; j < 4; j++){
        int m = bm + wm + i*16 + q*4;
        int n = bn + wn + j*16 + cc;
        float bv = bias[n];
        #pragma unroll
        for (int reg = 0; reg < 4; reg++)
          C[(size_t)(m + reg)*Nd + n] = acc[i][j][reg] + bv;
      }
    }
  }
}

// ---------------- persistent recurrence ----------------
// grid = 128 blocks x 256 threads, all co-resident.
// Barrier: relaxed system-scope flags only — NO acquire/release (no L2 flush).
// __syncthreads() before the flag store drains vmcnt(0), so all this block's
// bypass stores are IF-visible before the flag becomes visible.
__device__ inline void gbar(unsigned* flags, unsigned ep){
  __syncthreads();
  if (threadIdx.x == 0) st_sys(flags + blockIdx.x, ep);
  if (threadIdx.x < 64){
    for (;;){
      unsigned v0 = ld_sys(flags + threadIdx.x);
      unsigned v1 = ld_sys(flags + 64 + threadIdx.x);
      if (__all((v0 >= ep) && (v1 >= ep))) break;
      __builtin_amdgcn_s_sleep(1);
    }
  }
  __syncthreads();
}

__global__ __launch_bounds__(256) void k_rec(float* __restrict__ seqT,
                                             const unsigned short* __restrict__ xp,
                                             const unsigned short* __restrict__ wh,
                                             unsigned* __restrict__ zbuf,
                                             unsigned* __restrict__ rhb,
                                             unsigned* __restrict__ hb,
                                             unsigned* flags){
  __shared__ float red[1536];
  __shared__ float tileA[16][33];
  __shared__ float tileB[16][17];
  int tid = threadIdx.x, w = tid >> 6, lane = tid & 63, q = lane >> 4, c = lane & 15;
  int blk = blockIdx.x;
  unsigned ep = 1;
  for (int t = 0; t < S_; t++){
    const float* ht = seqT + (size_t)t * 32768;
    // ---- phase A: z,r rows 0..2047; K split 4 ways across waves ----
    {
      int n0 = blk * 16;
      int wb = w*128 + q*4;                // word-row base for this wave/quad
      unsigned hv[64];
      #pragma unroll
      for (int i = 0; i < 8; i++){
        #pragma unroll
        for (int jj = 0; jj < 4; jj++){
          hv[i*8 + jj]     = ld_sys(hb + (wb + i*16 + jj)*32 + c);
          hv[i*8 + 4 + jj] = ld_sys(hb + (wb + i*16 + jj)*32 + c + 16);
        }
      }
      f32x4 acc0 = {0,0,0,0}, acc1 = {0,0,0,0};
      const unsigned short* wrow = wh + (size_t)(n0 + c)*H_ + w*256 + q*8;
      #pragma unroll
      for (int i = 0; i < 8; i++){
        short8 a0, a1;
        #pragma unroll
        for (int jj = 0; jj < 4; jj++){
          unsigned u0 = hv[i*8 + jj], u1 = hv[i*8 + 4 + jj];
          a0[2*jj]   = (short)(u0 & 0xffffu); a0[2*jj+1] = (short)(u0 >> 16);
          a1[2*jj]   = (short)(u1 & 0xffffu); a1[2*jj+1] = (short)(u1 >> 16);
        }
        short8 bfrg = *(const short8*)(wrow + i*32);
        acc0 = __builtin_amdgcn_mfma_f32_16x16x32_bf16(a0, bfrg, acc0, 0, 0, 0);
        acc1 = __builtin_amdgcn_mfma_f32_16x16x32_bf16(a1, bfrg, acc1, 0, 0, 0);
      }
      if (w > 0){
        #pragma unroll
        for (int i = 0; i < 4; i++){
          red[(w-1)*512 + lane*8 + i]     = acc0[i];
          red[(w-1)*512 + lane*8 + 4 + i] = acc1[i];
        }
      }
      __syncthreads();
      if (w == 0){
        #pragma unroll
        for (int r = 0; r < 3; r++)
          #pragma unroll
          for (int i = 0; i < 4; i++){
            acc0[i] += red[r*512 + lane*8 + i];
            acc1[i] += red[r*512 + lane*8 + 4 + i];
          }
        int gr = n0 + c;
        const unsigned short* xpp = xp + ((size_t)t*H3 + gr)*32;
        #pragma unroll
        for (int mt = 0; mt < 2; mt++){
          #pragma unroll
          for (int reg = 0; reg < 4; reg++){
            int b = mt*16 + q*4 + reg;
            float pre = (mt ? acc1[reg] : acc0[reg]) + bf2f(xpp[b]);
            float sg = 1.0f / (1.0f + __expf(-pre));
            if (blk < 64){
              st_sys(zbuf + gr*32 + b, __builtin_bit_cast(unsigned, sg));
            } else {
              int hh = gr - 1024;
              unsigned hw = ld_sys(hb + (hh >> 1)*32 + b);
              float hval = bf2f((unsigned short)((c & 1) ? (hw >> 16) : (hw & 0xffffu)));
              tileA[c][b] = sg * hval;
            }
          }
        }
      }
      if (blk >= 64){
        __syncthreads();
        int kk = tid >> 5, b = tid & 31;   // 256 threads = 8 word-rows x 32 b
        float lo = tileA[2*kk][b], hi = tileA[2*kk+1][b];
        unsigned pk = (unsigned)f2bf(lo) | ((unsigned)f2bf(hi) << 16);
        int hbase = blk*8 - 512;           // (blk*16-1024)/2
        st_sys(rhb + (hbase + kk)*32 + b, pk);
      }
    }
    gbar(flags, ep++);
    // ---- phase B: g rows 2048..3071 on (r.h), then h update ----
    {
      int nt = blk >> 1, mt = blk & 1;
      int n0 = nt * 16;
      int wb = w*128 + q*4;
      unsigned hv[32];
      #pragma unroll
      for (int i = 0; i < 8; i++)
        #pragma unroll
        for (int jj = 0; jj < 4; jj++)
          hv[i*4 + jj] = ld_sys(rhb + (wb + i*16 + jj)*32 + mt*16 + c);
      f32x4 acc = {0,0,0,0};
      const unsigned short* wrow = wh + (size_t)(2048 + n0 + c)*H_ + w*256 + q*8;
      #pragma unroll
      for (int i = 0; i < 8; i++){
        short8 a0;
        #pragma unroll
        for (int jj = 0; jj < 4; jj++){
          unsigned u0 = hv[i*4 + jj];
          a0[2*jj] = (short)(u0 & 0xffffu); a0[2*jj+1] = (short)(u0 >> 16);
        }
        short8 bfrg = *(const short8*)(wrow + i*32);
        acc = __builtin_amdgcn_mfma_f32_16x16x32_bf16(a0, bfrg, acc, 0, 0, 0);
      }
      if (w > 0){
        #pragma unroll
        for (int i = 0; i < 4; i++) red[(w-1)*512 + lane*8 + i] = acc[i];
      }
      __syncthreads();
      if (w == 0){
        #pragma unroll
        for (int r = 0; r < 3; r++)
          #pragma unroll
          for (int i = 0; i < 4; i++) acc[i] += red[r*512 + lane*8 + i];
        int n = n0 + c;
        const unsigned short* xpp = xp + ((size_t)t*H3 + 2048 + n)*32;
        float* hn = seqT + (size_t)(t+1)*32768;
        #pragma unroll
        for (int reg = 0; reg < 4; reg++){
          int b = mt*16 + q*4 + reg;
          float pre = acc[reg] + bf2f(xpp[b]);
          float g = tanhf(pre);
          float z = __builtin_bit_cast(float, ld_sys(zbuf + n*32 + b));
          float h = ht[n*32 + b];             // owner-local fp32 (cached)
          float hnv = z*h + (1.0f - z)*g;
          hn[n*32 + b] = hnv;                 // owner-local fp32 (cached)
          tileB[c][q*4 + reg] = hnv;
        }
      }
      __syncthreads();
      if (tid < 128){
        int kk = tid >> 4, bl = tid & 15;
        unsigned pk = (unsigned)f2bf(tileB[2*kk][bl]) | ((unsigned)f2bf(tileB[2*kk+1][bl]) << 16);
        st_sys(hb + ((n0 >> 1) + kk)*32 + mt*16 + bl, pk);
      }
    }
    gbar(flags, ep++);
  }
}

extern "C" void kernel_launch(void* const* d_in, const int* in_sizes, int n_in,
                              void* d_out, int out_size, void* d_ws, size_t ws_size,
                              hipStream_t stream){
  (void)in_sizes; (void)n_in; (void)out_size;
  if (ws_size < WS_NEED) return;

  const float* x    = (const float*)d_in[0];
  const float* h0   = (const float*)d_in[1];
  const float* Wx0  = (const float*)d_in[2];
  const float* Wh0  = (const float*)d_in[3];
  const float* bh0  = (const float*)d_in[4];
  const float* Wx   = (const float*)d_in[5];
  const float* Wh   = (const float*)d_in[6];
  const float* bh   = (const float*)d_in[7];
  const float* Wout = (const float*)d_in[8];
  const float* bout = (const float*)d_in[9];
  float* out = (float*)d_out;

  char* ws = (char*)d_ws;
  unsigned short* xp    = (unsigned short*)(ws + XP_OFF);
  float*          seqT  = (float*)(ws + SEQT_OFF);
  unsigned short* xbf   = (unsigned short*)(ws + XBF_OFF);
  unsigned short* whbf  = (unsigned short*)(ws + WHBF_OFF);
  unsigned short* wx0b  = (unsigned short*)(ws + WX0_OFF);
  unsigned short* wx12b = (unsigned short*)(ws + WX12_OFF);
  unsigned short* woutb = (unsigned short*)(ws + WOUT_OFF);
  unsigned*       zbuf  = (unsigned*)(ws + ZBUF_OFF);
  unsigned*       rhb   = (unsigned*)(ws + RHB_OFF);
  unsigned*       hb    = (unsigned*)(ws + HB_OFF);
  unsigned*       flags = (unsigned*)(ws + FLAG_OFF);

  hipMemsetAsync(ws + FLAG_OFF, 0, 4096, stream);

  k_conv<<<(3145728+255)/256, 256, 0, stream>>>(Wh0, whbf, 3145728);
  k_conv<<<(6291456+255)/256, 256, 0, stream>>>(Wh,  whbf + 3145728, 6291456);
  k_conv<<<(786432+255)/256,  256, 0, stream>>>(Wx0, wx0b, 786432);
  k_conv<<<(6291456+255)/256, 256, 0, stream>>>(Wx,  wx12b, 6291456);
  k_conv<<<(262144+255)/256,  256, 0, stream>>>(Wout, woutb, 262144);
  k_convx<<<16384, 256, 0, stream>>>(x, xbf);

  for (int l = 0; l < 3; l++){
    k_seth0<<<128, 256, 0, stream>>>(h0, seqT, hb, l);
    const unsigned short* wxl = (l == 0) ? wx0b : (wx12b + (size_t)(l-1)*3145728);
    const float* biasl = (l == 0) ? bh0 : (bh + (size_t)(l-1)*3072);
    int Kd = (l == 0) ? 256 : 1024;
    dim3 g(24, 128);
    k_gemm<<<g, 256, 0, stream>>>(xbf, wxl, biasl, (void*)xp, Kd, 0, H3);
    k_rec<<<128, 256, 0, stream>>>(seqT, xp, whbf + (size_t)l*3145728, zbuf, rhb, hb, flags + (size_t)l*128);
    k_final<<<128, 256, 0, stream>>>(seqT, out, l);
    k_transp<<<dim3(512, 16), 256, 0, stream>>>(seqT, xbf);
  }
  dim3 g2(2, 128);
  k_gemm<<<g2, 256, 0, stream>>>(xbf, woutb, bout, (void*)out, 1024, 1, 256);
}

// Round 3
// 18382.945 us; speedup vs baseline: 2.4370x; 1.1863x over previous
//
#include <hip/hip_runtime.h>
#include <cstdint>
#include <cstddef>

#define B_  32
#define S_  512
#define I_  256
#define H_  1024
#define O_  256
#define H3  3072
#define OUT_OFF 4194304  // B*S*O

typedef __attribute__((ext_vector_type(8))) short  short8;
typedef __attribute__((ext_vector_type(4))) float  f32x4;
typedef __attribute__((ext_vector_type(4))) unsigned short us4;
typedef __attribute__((ext_vector_type(4))) unsigned int   u32x4;

#define MFMA __builtin_amdgcn_mfma_f32_16x16x32_bf16

// ---- workspace layout (bytes) ----
static const size_t XP_OFF    = 0;            // bf16 [512][3072][32] (layer0 xproj, bias folded)
static const size_t H2_OFF    = 100663296;    // bf16 [16384][1024]  (layer2 outputs, row=s*32+b)
static const size_t XBF_OFF   = 134217728;    // bf16 [16384][256]
static const size_t WX0B_OFF  = 142606336;    // bf16 [3072][256]
static const size_t WZR0_OFF  = 144179200;    // bf16 [2048][1024]   (Wh0 gates z,r)
static const size_t WG0_OFF   = 148373504;    // bf16 [1024][1024]   (Wh0 gate g)
static const size_t WZR1_OFF  = 150470656;    // bf16 [2048][2048]   ([Wh1|Wx1] z,r)
static const size_t WGX1_OFF  = 158859264;    // bf16 [1024][1024]   (Wx1 gate g)
static const size_t WG1_OFF   = 160956416;    // bf16 [1024][1024]   (Wh1 gate g)
static const size_t WZR2_OFF  = 163053568;
static const size_t WGX2_OFF  = 171442176;
static const size_t WG2_OFF   = 173539328;
static const size_t WOUTB_OFF = 175636480;    // bf16 [256][1024]
static const size_t HB_OFF    = 176160768;    // 3 x 64KB packed bf16 h  [512 wr][32 b]
static const size_t RHB_OFF   = 176357376;    // 3 x 64KB packed bf16 r*h
static const size_t FLAG_OFF  = 176553984;    // 4096
static const size_t WS_NEED   = 176558080;

__device__ inline unsigned short f2bf(float f){
  unsigned u = __builtin_bit_cast(unsigned, f);
  unsigned r = u + 0x7fffu + ((u >> 16) & 1u);
  return (unsigned short)(r >> 16);
}
__device__ inline float bf2f(unsigned short s){
  unsigned u = ((unsigned)s) << 16;
  return __builtin_bit_cast(float, u);
}

// bypass (IF coherence point) ops: relaxed system-scope -> sc0 sc1, no cache flush
__device__ inline unsigned ld_sys(const unsigned* p){
  return __hip_atomic_load(p, __ATOMIC_RELAXED, __HIP_MEMORY_SCOPE_SYSTEM);
}
__device__ inline void st_sys(unsigned* p, unsigned v){
  __hip_atomic_store(p, v, __ATOMIC_RELAXED, __HIP_MEMORY_SCOPE_SYSTEM);
}

__device__ inline short8 mk8(const unsigned* h){
  u32x4 u; u.x = h[0]; u.y = h[1]; u.z = h[2]; u.w = h[3];
  return __builtin_bit_cast(short8, u);
}

// ---------------- simple converts ----------------
__global__ void k_conv(const float* __restrict__ src, unsigned short* __restrict__ dst, int n){
  int i = blockIdx.x*256 + threadIdx.x;
  if (i < n) dst[i] = f2bf(src[i]);
}

// pack [Wh|Wx] z,r rows: dst[n][k], n in [0,2048), k in [0,2048)
__global__ void k_packzr(const float* __restrict__ Wh, const float* __restrict__ Wx,
                         unsigned short* __restrict__ dst){
  size_t i = (size_t)blockIdx.x*256 + threadIdx.x;   // < 4194304
  int k = (int)(i & 2047);
  int n = (int)(i >> 11);
  float v = (k < 1024) ? Wh[(size_t)n*1024 + k] : Wx[(size_t)n*1024 + (k - 1024)];
  dst[i] = f2bf(v);
}

// x [B][S][I] fp32 -> xbf rows (s*32+b) x 256 bf16
__global__ void k_convx(const float* __restrict__ x, unsigned short* __restrict__ xbf){
  int row = blockIdx.x;          // s*32+b
  int s = row >> 5, b = row & 31;
  int i = threadIdx.x;           // 0..255
  xbf[(size_t)row*I_ + i] = f2bf(x[((size_t)b*S_ + s)*I_ + i]);
}

// ---------------- bf16 MFMA GEMM: C = A * Bw^T + bias ----------------
// mode0: Cout = xp bf16 at [s][n][b] (m = s*32+b), bias fp32[n]
// mode1: Cout = fp32 at m*Nd + n (m = b*512+s, A row phys = (m&511)*32+(m>>9))
__global__ __launch_bounds__(256) void k_gemm(const unsigned short* __restrict__ A,
                                              const unsigned short* __restrict__ Bw,
                                              const float* __restrict__ bias,
                                              void* __restrict__ Cout,
                                              int Kd, int mode, int Nd){
  __shared__ __align__(16) unsigned short lA[128*40];
  __shared__ __align__(16) unsigned short lB[128*40];
  int bm = blockIdx.y * 128, bn = blockIdx.x * 128;
  int tid = threadIdx.x;
  int w = tid >> 6, lane = tid & 63, q = lane >> 4, cc = lane & 15;
  int wm = (w >> 1) * 64, wn = (w & 1) * 64;
  f32x4 acc[4][4] = {};
  for (int k0 = 0; k0 < Kd; k0 += 32){
    #pragma unroll
    for (int i = 0; i < 2; i++){
      int idx = tid + i*256;          // 0..511
      int r = idx >> 2, ch = idx & 3;
      int m = bm + r;
      int arow = (mode == 0) ? m : ((m & 511)*32 + (m >> 9));
      *(u32x4*)(lA + r*40 + ch*8) = *(const u32x4*)(A + (size_t)arow*Kd + k0 + ch*8);
      *(u32x4*)(lB + r*40 + ch*8) = *(const u32x4*)(Bw + (size_t)(bn + r)*Kd + k0 + ch*8);
    }
    __syncthreads();
    short8 af[4], bfv[4];
    #pragma unroll
    for (int i = 0; i < 4; i++) af[i]  = *(const short8*)(lA + (wm + i*16 + cc)*40 + q*8);
    #pragma unroll
    for (int i = 0; i < 4; i++) bfv[i] = *(const short8*)(lB + (wn + i*16 + cc)*40 + q*8);
    #pragma unroll
    for (int i = 0; i < 4; i++)
      #pragma unroll
      for (int j = 0; j < 4; j++)
        acc[i][j] = MFMA(af[i], bfv[j], acc[i][j], 0, 0, 0);
    __syncthreads();
  }
  if (mode == 0){
    unsigned short* xp = (unsigned short*)Cout;
    #pragma unroll
    for (int i = 0; i < 4; i++){
      #pragma unroll
      for (int j = 0; j < 4; j++){
        int m = bm + wm + i*16 + q*4;
        int n = bn + wn + j*16 + cc;
        float bv = bias[n];
        int s = m >> 5, b0 = m & 31;
        us4 pk;
        #pragma unroll
        for (int reg = 0; reg < 4; reg++) pk[reg] = f2bf(acc[i][j][reg] + bv);
        *(us4*)(xp + ((size_t)s*H3 + n)*32 + b0) = pk;
      }
    }
  } else {
    float* C = (float*)Cout;
    #pragma unroll
    for (int i = 0; i < 4; i++){
      #pragma unroll
      for (int j = 0; j < 4; j++){
        int m = bm + wm + i*16 + q*4;
        int n = bn + wn + j*16 + cc;
        float bv = bias[n];
        #pragma unroll
        for (int reg = 0; reg < 4; reg++)
          C[(size_t)(m + reg)*Nd + n] = acc[i][j][reg] + bv;
      }
    }
  }
}

// ---------------- fused 3-layer pipelined persistent recurrence ----------------
// 192 blocks: blk>>6 = layer, blk&63 = j (rows 16j..16j+16 of each gate).
__device__ inline void gbar(unsigned* flags, unsigned ep){
  __syncthreads();
  if (threadIdx.x == 0) st_sys(flags + blockIdx.x, ep);
  if (threadIdx.x < 64){
    for (;;){
      unsigned v0 = ld_sys(flags + threadIdx.x);
      unsigned v1 = ld_sys(flags + 64 + threadIdx.x);
      unsigned v2 = ld_sys(flags + 128 + threadIdx.x);
      if (__all((v0 >= ep) && (v1 >= ep) && (v2 >= ep))) break;
      __builtin_amdgcn_s_sleep(1);
    }
  }
  __syncthreads();
}

__global__ __launch_bounds__(256, 1) void k_fused(char* __restrict__ ws,
                                                  const float* __restrict__ h0,
                                                  const float* __restrict__ bh,
                                                  float* __restrict__ outp){
  __shared__ float red[3*1088];
  __shared__ float redg[64*9];
  __shared__ float hloc[16][33];
  __shared__ float gxloc[16][33];
  __shared__ float rtile[16][33];

  const int tid = threadIdx.x;
  const int w = tid >> 6, lane = tid & 63, q = lane >> 4, c = lane & 15;
  const int blk = blockIdx.x, l = blk >> 6, j = blk & 63, n0 = j << 4;

  const unsigned short* xp = (const unsigned short*)(ws + XP_OFF);
  unsigned short* h2       = (unsigned short*)(ws + H2_OFF);
  const unsigned short* Wzr = (const unsigned short*)(ws + (l==0 ? WZR0_OFF : (l==1 ? WZR1_OFF : WZR2_OFF)));
  const unsigned short* Wgx = (const unsigned short*)(ws + (l==1 ? WGX1_OFF : WGX2_OFF));
  const unsigned short* Wg  = (const unsigned short*)(ws + (l==0 ? WG0_OFF  : (l==1 ? WG1_OFF  : WG2_OFF)));
  unsigned* hb    = (unsigned*)(ws + HB_OFF);
  unsigned* rhb   = (unsigned*)(ws + RHB_OFF);
  unsigned* flags = (unsigned*)(ws + FLAG_OFF);
  unsigned* hbl   = hb + l*16384;
  const unsigned* hbm1 = hb + (l-1)*16384;   // valid only l>0
  unsigned* rhbl  = rhb + l*16384;
  const float* bias = bh + (size_t)(l > 0 ? l-1 : 0)*H3;

  // ---- init h state ----
  #pragma unroll
  for (int i = 0; i < 2; i++){
    int idx = tid + i*256;          // n*32+b
    int n = idx >> 5, b = idx & 31;
    hloc[n][b] = h0[((size_t)b*3 + l)*H_ + n0 + n];
  }
  __syncthreads();
  {
    int wrl = tid >> 5, b = tid & 31;
    unsigned pk = (unsigned)f2bf(hloc[2*wrl][b]) | ((unsigned)f2bf(hloc[2*wrl+1][b]) << 16);
    st_sys(hbl + (j*8 + wrl)*32 + b, pk);
  }
  unsigned ep = 1;
  gbar(flags, ep++);

  float zreg[8];

  for (int T = 0; T < 514; T++){
    const int t = T - l;
    const bool active = (t >= 0) && (t < 512);
    // ================= phase A: z, r (and gx for l>0) =================
    if (active){
      f32x4 az0 = {0,0,0,0}, az1 = {0,0,0,0}, ar0 = {0,0,0,0}, ar1 = {0,0,0,0};
      f32x4 ag0 = {0,0,0,0}, ag1 = {0,0,0,0};
      if (l == 0){
        unsigned hA0[32], hA1[32];
        const unsigned* src = hbl + (size_t)(w*128)*32;
        #pragma unroll
        for (int i = 0; i < 8; i++)
          #pragma unroll
          for (int jj = 0; jj < 4; jj++){
            int wr = (q*4 + i*16 + jj)*32;
            hA0[i*4+jj] = ld_sys(src + wr + c);
            hA1[i*4+jj] = ld_sys(src + wr + c + 16);
          }
        const unsigned short* wz  = Wzr + (size_t)(n0 + c)*1024 + w*256 + q*8;
        const unsigned short* wrp = wz + (size_t)1024*1024;
        #pragma unroll
        for (int i = 0; i < 8; i++){
          short8 a0 = mk8(hA0 + i*4), a1 = mk8(hA1 + i*4);
          short8 bz = *(const short8*)(wz  + i*32);
          short8 br = *(const short8*)(wrp + i*32);
          az0 = MFMA(a0, bz, az0, 0,0,0); az1 = MFMA(a1, bz, az1, 0,0,0);
          ar0 = MFMA(a0, br, ar0, 0,0,0); ar1 = MFMA(a1, br, ar1, 0,0,0);
        }
      } else {
        unsigned hA0[32], hA1[32], hB0[32], hB1[32];
        const int cwr0 = w*256, cwr1 = w*256 + 128;       // concat word-rows
        const unsigned* s0 = (cwr0 < 512) ? (hbl + (size_t)cwr0*32) : (hbm1 + (size_t)(cwr0-512)*32);
        const unsigned* s1 = (cwr1 < 512) ? (hbl + (size_t)cwr1*32) : (hbm1 + (size_t)(cwr1-512)*32);
        #pragma unroll
        for (int i = 0; i < 8; i++)
          #pragma unroll
          for (int jj = 0; jj < 4; jj++){
            int wr = (q*4 + i*16 + jj)*32;
            hA0[i*4+jj] = ld_sys(s0 + wr + c);
            hA1[i*4+jj] = ld_sys(s0 + wr + c + 16);
            hB0[i*4+jj] = ld_sys(s1 + wr + c);
            hB1[i*4+jj] = ld_sys(s1 + wr + c + 16);
          }
        const unsigned short* wz0 = Wzr + (size_t)(n0 + c)*2048 + cwr0*2 + q*8;
        const unsigned short* wr0 = wz0 + (size_t)1024*2048;
        const bool dogx = (w >= 2);   // waves 2,3 hold h_{l-1} slices
        const unsigned short* wg0 = Wgx + (size_t)(n0 + c)*1024 + (cwr0 - 512)*2 + q*8;
        #pragma unroll
        for (int i = 0; i < 8; i++){
          short8 a0 = mk8(hA0 + i*4), a1 = mk8(hA1 + i*4);
          short8 bz = *(const short8*)(wz0 + i*32);
          short8 br = *(const short8*)(wr0 + i*32);
          az0 = MFMA(a0, bz, az0, 0,0,0); az1 = MFMA(a1, bz, az1, 0,0,0);
          ar0 = MFMA(a0, br, ar0, 0,0,0); ar1 = MFMA(a1, br, ar1, 0,0,0);
          if (dogx){
            short8 bg = *(const short8*)(wg0 + i*32);
            ag0 = MFMA(a0, bg, ag0, 0,0,0); ag1 = MFMA(a1, bg, ag1, 0,0,0);
          }
        }
        const unsigned short* wz1 = Wzr + (size_t)(n0 + c)*2048 + cwr1*2 + q*8;
        const unsigned short* wr1 = wz1 + (size_t)1024*2048;
        const unsigned short* wg1 = Wgx + (size_t)(n0 + c)*1024 + (cwr1 - 512)*2 + q*8;
        #pragma unroll
        for (int i = 0; i < 8; i++){
          short8 a0 = mk8(hB0 + i*4), a1 = mk8(hB1 + i*4);
          short8 bz = *(const short8*)(wz1 + i*32);
          short8 br = *(const short8*)(wr1 + i*32);
          az0 = MFMA(a0, bz, az0, 0,0,0); az1 = MFMA(a1, bz, az1, 0,0,0);
          ar0 = MFMA(a0, br, ar0, 0,0,0); ar1 = MFMA(a1, br, ar1, 0,0,0);
          if (dogx){
            short8 bg = *(const short8*)(wg1 + i*32);
            ag0 = MFMA(a0, bg, ag0, 0,0,0); ag1 = MFMA(a1, bg, ag1, 0,0,0);
          }
        }
      }
      // cross-wave reduce
      if (w > 0){
        #pragma unroll
        for (int i = 0; i < 4; i++){
          red[(w-1)*1088 + lane*17 + i]      = az0[i];
          red[(w-1)*1088 + lane*17 + 4 + i]  = az1[i];
          red[(w-1)*1088 + lane*17 + 8 + i]  = ar0[i];
          red[(w-1)*1088 + lane*17 + 12 + i] = ar1[i];
        }
      }
      if (l > 0 && w == 3){
        #pragma unroll
        for (int i = 0; i < 4; i++){
          redg[lane*9 + i]     = ag0[i];
          redg[lane*9 + 4 + i] = ag1[i];
        }
      }
      __syncthreads();
      if (w == 0){
        #pragma unroll
        for (int r = 0; r < 3; r++)
          #pragma unroll
          for (int i = 0; i < 4; i++){
            az0[i] += red[r*1088 + lane*17 + i];
            az1[i] += red[r*1088 + lane*17 + 4 + i];
            ar0[i] += red[r*1088 + lane*17 + 8 + i];
            ar1[i] += red[r*1088 + lane*17 + 12 + i];
          }
        float bz = 0.f, brr = 0.f;
        const unsigned short* xpz = xp + ((size_t)t*H3 + n0 + c)*32;
        const unsigned short* xpr = xp + ((size_t)t*H3 + 1024 + n0 + c)*32;
        if (l > 0){ bz = bias[n0 + c]; brr = bias[1024 + n0 + c]; }
        #pragma unroll
        for (int mt = 0; mt < 2; mt++)
          #pragma unroll
          for (int reg = 0; reg < 4; reg++){
            int b = mt*16 + q*4 + reg;
            float zp = (mt ? az1[reg] : az0[reg]);
            float rp = (mt ? ar1[reg] : ar0[reg]);
            if (l == 0){ zp += bf2f(xpz[b]); rp += bf2f(xpr[b]); }
            else       { zp += bz;           rp += brr; }
            float zv = 1.0f/(1.0f + __expf(-zp));
            float rv = 1.0f/(1.0f + __expf(-rp));
            zreg[mt*4 + reg] = zv;
            rtile[c][b] = rv * hloc[c][b];
          }
      }
      if (l > 0 && w == 2){
        float bg = bias[2048 + n0 + c];
        #pragma unroll
        for (int mt = 0; mt < 2; mt++)
          #pragma unroll
          for (int reg = 0; reg < 4; reg++){
            int b = mt*16 + q*4 + reg;
            float gv = (mt ? ag1[reg] : ag0[reg]) + redg[lane*9 + mt*4 + reg] + bg;
            gxloc[c][b] = gv;
          }
      }
      __syncthreads();
      {
        int wrl = tid >> 5, b = tid & 31;
        unsigned pk = (unsigned)f2bf(rtile[2*wrl][b]) | ((unsigned)f2bf(rtile[2*wrl+1][b]) << 16);
        st_sys(rhbl + (j*8 + wrl)*32 + b, pk);
      }
    }
    gbar(flags, ep++);
    // ================= phase B: g matvec + h update =================
    if (active){
      f32x4 ag0 = {0,0,0,0}, ag1 = {0,0,0,0};
      {
        unsigned hA0[32], hA1[32];
        const unsigned* src = rhbl + (size_t)(w*128)*32;
        #pragma unroll
        for (int i = 0; i < 8; i++)
          #pragma unroll
          for (int jj = 0; jj < 4; jj++){
            int wr = (q*4 + i*16 + jj)*32;
            hA0[i*4+jj] = ld_sys(src + wr + c);
            hA1[i*4+jj] = ld_sys(src + wr + c + 16);
          }
        const unsigned short* wg = Wg + (size_t)(n0 + c)*1024 + w*256 + q*8;
        #pragma unroll
        for (int i = 0; i < 8; i++){
          short8 a0 = mk8(hA0 + i*4), a1 = mk8(hA1 + i*4);
          short8 bg = *(const short8*)(wg + i*32);
          ag0 = MFMA(a0, bg, ag0, 0,0,0); ag1 = MFMA(a1, bg, ag1, 0,0,0);
        }
      }
      if (w > 0){
        #pragma unroll
        for (int i = 0; i < 4; i++){
          red[(w-1)*1088 + lane*17 + i]     = ag0[i];
          red[(w-1)*1088 + lane*17 + 4 + i] = ag1[i];
        }
      }
      __syncthreads();
      if (w == 0){
        #pragma unroll
        for (int r = 0; r < 3; r++)
          #pragma unroll
          for (int i = 0; i < 4; i++){
            ag0[i] += red[r*1088 + lane*17 + i];
            ag1[i] += red[r*1088 + lane*17 + 4 + i];
          }
        const unsigned short* xpg = xp + ((size_t)t*H3 + 2048 + n0 + c)*32;
        #pragma unroll
        for (int mt = 0; mt < 2; mt++)
          #pragma unroll
          for (int reg = 0; reg < 4; reg++){
            int b = mt*16 + q*4 + reg;
            float gp = (mt ? ag1[reg] : ag0[reg]);
            gp += (l == 0) ? bf2f(xpg[b]) : gxloc[c][b];
            float gv = tanhf(gp);
            float zv = zreg[mt*4 + reg];
            float hv = hloc[c][b];
            float hn = zv*hv + (1.0f - zv)*gv;
            hloc[c][b] = hn;
            if (l == 2) h2[((size_t)t*32 + b)*1024 + n0 + c] = f2bf(hn);
            if (t == 511) outp[OUT_OFF + ((size_t)b*3 + l)*H_ + n0 + c] = hn;
          }
      }
      __syncthreads();
      {
        int wrl = tid >> 5, b = tid & 31;
        unsigned pk = (unsigned)f2bf(hloc[2*wrl][b]) | ((unsigned)f2bf(hloc[2*wrl+1][b]) << 16);
        st_sys(hbl + (j*8 + wrl)*32 + b, pk);
      }
    }
    gbar(flags, ep++);
  }
}

extern "C" void kernel_launch(void* const* d_in, const int* in_sizes, int n_in,
                              void* d_out, int out_size, void* d_ws, size_t ws_size,
                              hipStream_t stream){
  (void)in_sizes; (void)n_in; (void)out_size;
  if (ws_size < WS_NEED) return;

  const float* x    = (const float*)d_in[0];
  const float* h0   = (const float*)d_in[1];
  const float* Wx0  = (const float*)d_in[2];
  const float* Wh0  = (const float*)d_in[3];
  const float* bh0  = (const float*)d_in[4];
  const float* Wx   = (const float*)d_in[5];
  const float* Wh   = (const float*)d_in[6];
  const float* bh   = (const float*)d_in[7];
  const float* Wout = (const float*)d_in[8];
  const float* bout = (const float*)d_in[9];
  float* out = (float*)d_out;

  char* ws = (char*)d_ws;
  unsigned short* xp    = (unsigned short*)(ws + XP_OFF);
  unsigned short* h2    = (unsigned short*)(ws + H2_OFF);
  unsigned short* xbf   = (unsigned short*)(ws + XBF_OFF);
  unsigned short* wx0b  = (unsigned short*)(ws + WX0B_OFF);
  unsigned short* wzr0  = (unsigned short*)(ws + WZR0_OFF);
  unsigned short* wg0   = (unsigned short*)(ws + WG0_OFF);
  unsigned short* wzr1  = (unsigned short*)(ws + WZR1_OFF);
  unsigned short* wgx1  = (unsigned short*)(ws + WGX1_OFF);
  unsigned short* wg1   = (unsigned short*)(ws + WG1_OFF);
  unsigned short* wzr2  = (unsigned short*)(ws + WZR2_OFF);
  unsigned short* wgx2  = (unsigned short*)(ws + WGX2_OFF);
  unsigned short* wg2   = (unsigned short*)(ws + WG2_OFF);
  unsigned short* woutb = (unsigned short*)(ws + WOUTB_OFF);

  hipMemsetAsync(ws + FLAG_OFF, 0, 4096, stream);

  // weight preparation
  k_conv<<<3072, 256, 0, stream>>>(Wx0, wx0b, 786432);
  k_conv<<<8192, 256, 0, stream>>>(Wh0, wzr0, 2097152);
  k_conv<<<4096, 256, 0, stream>>>(Wh0 + 2097152, wg0, 1048576);
  k_packzr<<<16384, 256, 0, stream>>>(Wh, Wx, wzr1);
  k_conv<<<4096, 256, 0, stream>>>(Wx + 2097152, wgx1, 1048576);
  k_conv<<<4096, 256, 0, stream>>>(Wh + 2097152, wg1, 1048576);
  k_packzr<<<16384, 256, 0, stream>>>(Wh + 3145728, Wx + 3145728, wzr2);
  k_conv<<<4096, 256, 0, stream>>>(Wx + 5242880, wgx2, 1048576);
  k_conv<<<4096, 256, 0, stream>>>(Wh + 5242880, wg2, 1048576);
  k_conv<<<1024, 256, 0, stream>>>(Wout, woutb, 262144);
  k_convx<<<16384, 256, 0, stream>>>(x, xbf);

  // layer-0 input projection (bias folded)
  {
    dim3 g(24, 128);
    k_gemm<<<g, 256, 0, stream>>>(xbf, wx0b, bh0, (void*)xp, 256, 0, H3);
  }
  // fused pipelined recurrence (all 3 layers)
  k_fused<<<192, 256, 0, stream>>>(ws, h0, bh, out);
  // output projection
  {
    dim3 g(2, 128);
    k_gemm<<<g, 256, 0, stream>>>(h2, woutb, bout, (void*)out, 1024, 1, 256);
  }
}

// Round 4
// 14916.162 us; speedup vs baseline: 3.0034x; 1.2324x over previous
//
#include <hip/hip_runtime.h>
#include <cstdint>
#include <cstddef>

#define S_  512
#define H_  1024
#define H3  3072
#define OUT_OFF 4194304  // B*S*O

typedef __attribute__((ext_vector_type(8))) short  short8;
typedef __attribute__((ext_vector_type(4))) float  f32x4;
typedef __attribute__((ext_vector_type(4))) unsigned short us4;
typedef __attribute__((ext_vector_type(4))) unsigned int   u32x4;
typedef unsigned long long u64;

#define MFMA __builtin_amdgcn_mfma_f32_16x16x32_bf16

// ---- workspace layout (bytes) ----
static const size_t XP_OFF    = 0;            // bf16 [512][3072][32] layer0 xproj (bias folded)
static const size_t H2_OFF    = 100663296;    // bf16 [16384][1024] layer2 outputs, row = t*32+b
static const size_t XBF_OFF   = 134217728;    // bf16 [16384][256]
static const size_t WX0B_OFF  = 142606336;    // bf16 [3072][256]
static const size_t WZR0_OFF  = 144179200;    // bf16 [2048][1024]
static const size_t WG0_OFF   = 148373504;    // bf16 [1024][1024]
static const size_t WZR1_OFF  = 150470656;    // bf16 [2048][2048]  [Wh1|Wx1] z,r
static const size_t WGX1_OFF  = 158859264;    // bf16 [1024][1024]
static const size_t WG1_OFF   = 160956416;    // bf16 [1024][1024]
static const size_t WZR2_OFF  = 163053568;
static const size_t WGX2_OFF  = 171442176;
static const size_t WG2_OFF   = 173539328;
static const size_t WOUTB_OFF = 175636480;    // bf16 [256][1024]
static const size_t HBU_OFF   = 176160768;    // u64 [3][32][256]  bf16 h, batch-major
static const size_t RHBU_OFF  = 176357376;    // u64 [3][32][256]  bf16 r*h, batch-major
static const size_t ZBU_OFF   = 176553984;    // u64 [3][1024][16] fp32-pair z
static const size_t GXB_OFF   = 176947200;    // u64 [3][1024][16] fp32-pair gx
static const size_t HROW_OFF  = 177340416;    // f32 [3][1024][32] block-local h state
static const size_t FLAG_OFF  = 177733632;    // 4096
static const size_t WS_NEED   = 177737728;

__device__ inline unsigned short f2bf(float f){
  unsigned u = __builtin_bit_cast(unsigned, f);
  unsigned r = u + 0x7fffu + ((u >> 16) & 1u);
  return (unsigned short)(r >> 16);
}
__device__ inline float bf2f(unsigned short s){
  unsigned u = ((unsigned)s) << 16;
  return __builtin_bit_cast(float, u);
}
__device__ inline unsigned ld_sys(const unsigned* p){
  return __hip_atomic_load(p, __ATOMIC_RELAXED, __HIP_MEMORY_SCOPE_SYSTEM);
}
__device__ inline void st_sys(unsigned* p, unsigned v){
  __hip_atomic_store(p, v, __ATOMIC_RELAXED, __HIP_MEMORY_SCOPE_SYSTEM);
}
__device__ inline u64 ld64(const u64* p){
  return __hip_atomic_load(p, __ATOMIC_RELAXED, __HIP_MEMORY_SCOPE_SYSTEM);
}
__device__ inline void st64(u64* p, u64 v){
  __hip_atomic_store(p, v, __ATOMIC_RELAXED, __HIP_MEMORY_SCOPE_SYSTEM);
}
__device__ inline short8 mk8u(u64 a, u64 b){
  u32x4 u; u.x = (unsigned)a; u.y = (unsigned)(a >> 32); u.z = (unsigned)b; u.w = (unsigned)(b >> 32);
  return __builtin_bit_cast(short8, u);
}
__device__ inline u64 pk4(float a, float b, float c, float d){
  return (u64)f2bf(a) | ((u64)f2bf(b) << 16) | ((u64)f2bf(c) << 32) | ((u64)f2bf(d) << 48);
}
__device__ inline u64 pk2f(float a, float b){
  return (u64)__builtin_bit_cast(unsigned, a) | ((u64)__builtin_bit_cast(unsigned, b) << 32);
}
__device__ inline float lo32f(u64 u){ return __builtin_bit_cast(float, (unsigned)u); }
__device__ inline float hi32f(u64 u){ return __builtin_bit_cast(float, (unsigned)(u >> 32)); }

// ---------------- simple converts ----------------
__global__ void k_conv(const float* __restrict__ src, unsigned short* __restrict__ dst, int n){
  int i = blockIdx.x*256 + threadIdx.x;
  if (i < n) dst[i] = f2bf(src[i]);
}

__global__ void k_packzr(const float* __restrict__ Wh, const float* __restrict__ Wx,
                         unsigned short* __restrict__ dst){
  size_t i = (size_t)blockIdx.x*256 + threadIdx.x;   // < 4194304
  int k = (int)(i & 2047);
  int n = (int)(i >> 11);
  float v = (k < 1024) ? Wh[(size_t)n*1024 + k] : Wx[(size_t)n*1024 + (k - 1024)];
  dst[i] = f2bf(v);
}

__global__ void k_convx(const float* __restrict__ x, unsigned short* __restrict__ xbf){
  int row = blockIdx.x;          // s*32+b
  int s = row >> 5, b = row & 31;
  int i = threadIdx.x;           // 0..255
  xbf[(size_t)row*256 + i] = f2bf(x[((size_t)b*S_ + s)*256 + i]);
}

// ---------------- bf16 MFMA GEMM (from R3, proven) ----------------
__global__ __launch_bounds__(256) void k_gemm(const unsigned short* __restrict__ A,
                                              const unsigned short* __restrict__ Bw,
                                              const float* __restrict__ bias,
                                              void* __restrict__ Cout,
                                              int Kd, int mode, int Nd){
  __shared__ __align__(16) unsigned short lA[128*40];
  __shared__ __align__(16) unsigned short lB[128*40];
  int bm = blockIdx.y * 128, bn = blockIdx.x * 128;
  int tid = threadIdx.x;
  int w = tid >> 6, lane = tid & 63, q = lane >> 4, cc = lane & 15;
  int wm = (w >> 1) * 64, wn = (w & 1) * 64;
  f32x4 acc[4][4] = {};
  for (int k0 = 0; k0 < Kd; k0 += 32){
    #pragma unroll
    for (int i = 0; i < 2; i++){
      int idx = tid + i*256;
      int r = idx >> 2, ch = idx & 3;
      int m = bm + r;
      int arow = (mode == 0) ? m : ((m & 511)*32 + (m >> 9));
      *(u32x4*)(lA + r*40 + ch*8) = *(const u32x4*)(A + (size_t)arow*Kd + k0 + ch*8);
      *(u32x4*)(lB + r*40 + ch*8) = *(const u32x4*)(Bw + (size_t)(bn + r)*Kd + k0 + ch*8);
    }
    __syncthreads();
    short8 af[4], bfv[4];
    #pragma unroll
    for (int i = 0; i < 4; i++) af[i]  = *(const short8*)(lA + (wm + i*16 + cc)*40 + q*8);
    #pragma unroll
    for (int i = 0; i < 4; i++) bfv[i] = *(const short8*)(lB + (wn + i*16 + cc)*40 + q*8);
    #pragma unroll
    for (int i = 0; i < 4; i++)
      #pragma unroll
      for (int j = 0; j < 4; j++)
        acc[i][j] = MFMA(af[i], bfv[j], acc[i][j], 0, 0, 0);
    __syncthreads();
  }
  if (mode == 0){
    unsigned short* xp = (unsigned short*)Cout;
    #pragma unroll
    for (int i = 0; i < 4; i++){
      #pragma unroll
      for (int j = 0; j < 4; j++){
        int m = bm + wm + i*16 + q*4;
        int n = bn + wn + j*16 + cc;
        float bv = bias[n];
        int s = m >> 5, b0 = m & 31;
        us4 pk;
        #pragma unroll
        for (int reg = 0; reg < 4; reg++) pk[reg] = f2bf(acc[i][j][reg] + bv);
        *(us4*)(xp + ((size_t)s*H3 + n)*32 + b0) = pk;
      }
    }
  } else {
    float* C = (float*)Cout;
    #pragma unroll
    for (int i = 0; i < 4; i++){
      #pragma unroll
      for (int j = 0; j < 4; j++){
        int m = bm + wm + i*16 + q*4;
        int n = bn + wn + j*16 + cc;
        float bv = bias[n];
        #pragma unroll
        for (int reg = 0; reg < 4; reg++)
          C[(size_t)(m + reg)*Nd + n] = acc[i][j][reg] + bv;
      }
    }
  }
}

// ---------------- barrier: relaxed system flags, no cache flush ----------------
__device__ inline void gbar(unsigned* flags, unsigned ep){
  __syncthreads();
  if (threadIdx.x == 0) st_sys(flags + blockIdx.x, ep);
  if (threadIdx.x < 64){
    for (;;){
      unsigned v0 = ld_sys(flags + threadIdx.x);
      unsigned v1 = ld_sys(flags + 64 + threadIdx.x);
      unsigned v2 = ld_sys(flags + 128 + threadIdx.x);
      unsigned v3 = ld_sys(flags + 192 + threadIdx.x);
      if (__all((v0 >= ep) && (v1 >= ep) && (v2 >= ep) && (v3 >= ep))) break;
      __builtin_amdgcn_s_sleep(1);
    }
  }
  __syncthreads();
}

// matvec: one 16-row tile, this wave's K-slice; A from bypass u64 buffer (batch-major),
// weights from LDS. NITER k-iterations of 32. Rolling 4-iter prefetch.
template<int NITER>
__device__ inline void matvec(const u64* a0p, const u64* a1p, const unsigned short* wp,
                              f32x4& acc0, f32x4& acc1){
  u64 buf[2][4][2][2];
  #pragma unroll
  for (int ii = 0; ii < 4; ii++){
    buf[0][ii][0][0] = ld64(a0p + ii*8); buf[0][ii][0][1] = ld64(a0p + ii*8 + 1);
    buf[0][ii][1][0] = ld64(a1p + ii*8); buf[0][ii][1][1] = ld64(a1p + ii*8 + 1);
  }
  constexpr int NCH = NITER / 4;
  #pragma unroll
  for (int ch = 0; ch < NCH; ch++){
    const int cur = ch & 1, nxt = cur ^ 1;
    if (ch + 1 < NCH){
      #pragma unroll
      for (int ii = 0; ii < 4; ii++){
        int base = (ch + 1)*4 + ii;
        buf[nxt][ii][0][0] = ld64(a0p + base*8); buf[nxt][ii][0][1] = ld64(a0p + base*8 + 1);
        buf[nxt][ii][1][0] = ld64(a1p + base*8); buf[nxt][ii][1][1] = ld64(a1p + base*8 + 1);
      }
    }
    #pragma unroll
    for (int ii = 0; ii < 4; ii++){
      int it = ch*4 + ii;
      short8 bw = *(const short8*)(wp + it*32);
      acc0 = MFMA(mk8u(buf[cur][ii][0][0], buf[cur][ii][0][1]), bw, acc0, 0, 0, 0);
      acc1 = MFMA(mk8u(buf[cur][ii][1][0], buf[cur][ii][1][1]), bw, acc1, 0, 0, 0);
    }
  }
}

// ---------------- fused 3-layer pipelined persistent recurrence ----------------
// 256 blocks, 1/CU. Each block: one K2048 z/r tile (l1/l2) + one K1024 tile
// (l0 z/r or gx) in phase A; blocks 0..191 one Wg K1024 tile in phase B.
// All weights LDS-resident (~129KB). h fp32 state block-local (hrow).
__global__ __launch_bounds__(256, 1) void k_fused(char* __restrict__ ws,
                                                  const float* __restrict__ h0,
                                                  const float* __restrict__ bh,
                                                  float* __restrict__ outp){
  __shared__ __align__(16) unsigned short wlds[65920];  // 131840 B
  __shared__ __align__(16) float red[2][3][64][10];     // 15360 B
  __shared__ float rtA[16*33];                          // 2112 B
  __shared__ float rtB[16*33];                          // 2112 B

  const int tid = threadIdx.x;
  const int w = tid >> 6, lane = tid & 63, q = (lane >> 4) & 3, c = lane & 15;
  const int i = blockIdx.x;

  // roles
  const int lz   = 1 + (i >> 7);          // T2 tile layer: 1 or 2
  const int g2   = (i >> 6) & 1;          // T2 gate: 0=z, 1=r
  const int n2   = (i & 63) << 4;
  const bool isl0 = (i < 128);
  const int g1   = (i >> 6) & 1;          // l0 gate (valid if isl0)
  const int lgx  = 1 + ((i >> 6) & 1);    // gx layer (valid if !isl0)
  const int n1   = (i & 63) << 4;
  const bool hasB = (i < 192);
  const int lb   = i >> 6;                // phase-B layer (valid if hasB)
  const int nb   = (i & 63) << 4;

  const unsigned short* xp = (const unsigned short*)(ws + XP_OFF);
  u64* h2u   = (u64*)(ws + H2_OFF);
  u64* hbu   = (u64*)(ws + HBU_OFF);
  u64* rhbu  = (u64*)(ws + RHBU_OFF);
  u64* zbu   = (u64*)(ws + ZBU_OFF);
  u64* gxb   = (u64*)(ws + GXB_OFF);
  float* hrow = (float*)(ws + HROW_OFF);
  unsigned* flags = (unsigned*)(ws + FLAG_OFF);

  // ---- stage weights into LDS ----
  {
    const unsigned short* src2 = (const unsigned short*)(ws + (lz == 1 ? WZR1_OFF : WZR2_OFF))
                                 + (size_t)(g2*1024 + n2)*2048;
    for (int idx = tid; idx < 4096; idx += 256){
      int kc = idx & 255, row = idx >> 8;
      u32x4 v = *(const u32x4*)(src2 + (size_t)row*2048 + kc*8);
      *(u32x4*)(wlds + row*2056 + kc*8) = v;
    }
    const unsigned short* src1 = isl0
      ? (const unsigned short*)(ws + WZR0_OFF) + (size_t)(g1*1024 + n1)*1024
      : (const unsigned short*)(ws + (lgx == 1 ? WGX1_OFF : WGX2_OFF)) + (size_t)n1*1024;
    for (int idx = tid; idx < 2048; idx += 256){
      int kc = idx & 127, row = idx >> 7;
      u32x4 v = *(const u32x4*)(src1 + (size_t)row*1024 + kc*8);
      *(u32x4*)(wlds + 32896 + row*1032 + kc*8) = v;
    }
    if (hasB){
      const unsigned short* srcb = (const unsigned short*)(ws + (lb == 0 ? WG0_OFF : (lb == 1 ? WG1_OFF : WG2_OFF)))
                                   + (size_t)nb*1024;
      for (int idx = tid; idx < 2048; idx += 256){
        int kc = idx & 127, row = idx >> 7;
        u32x4 v = *(const u32x4*)(srcb + (size_t)row*1024 + kc*8);
        *(u32x4*)(wlds + 49408 + row*1032 + kc*8) = v;
      }
    }
  }
  const float biasT2 = bh[(size_t)(lz-1)*H3 + g2*1024 + n2 + c];
  const float biasGX = isl0 ? 0.f : bh[(size_t)(lgx-1)*H3 + 2048 + n1 + c];

  // ---- init fp32 h state (block-local) + bf16 broadcast copy ----
  if (hasB){
    for (int idx = tid; idx < 512; idx += 256){
      int n = idx >> 5, b = idx & 31;
      float v = h0[((size_t)b*3 + lb)*H_ + nb + n];
      hrow[((size_t)lb*1024 + nb + n)*32 + b] = v;
      rtA[n*33 + b] = v;
    }
  }
  __syncthreads();
  if (hasB && tid < 128){
    int b = tid & 31, p2 = tid >> 5;
    u64 pk = pk4(rtA[(4*p2+0)*33+b], rtA[(4*p2+1)*33+b], rtA[(4*p2+2)*33+b], rtA[(4*p2+3)*33+b]);
    st64(hbu + (size_t)lb*8192 + (size_t)b*256 + (nb >> 2) + p2, pk);
  }
  unsigned ep = 1;
  gbar(flags, ep); ep++;

  for (int T = 0; T < 514; T++){
    const int t2 = T - lz;
    const bool actT2 = (unsigned)t2 < 512u;
    const int t1 = isl0 ? T : (T - lgx);
    const bool actT1 = (unsigned)t1 < 512u;
    const int tb = T - lb;
    const bool actB = hasB && ((unsigned)tb < 512u);

    // ================= phase A =================
    f32x4 z20 = {0,0,0,0}, z21 = {0,0,0,0};
    f32x4 z10 = {0,0,0,0}, z11 = {0,0,0,0};
    if (actT2){
      const u64* ab = hbu + (size_t)((w < 2) ? lz : (lz-1))*8192;
      const u64* a0p = ab + (size_t)c*256 + (w & 1)*128 + q*2;
      const u64* a1p = a0p + 16*256;
      const unsigned short* wp = wlds + c*2056 + w*512 + q*8;
      matvec<16>(a0p, a1p, wp, z20, z21);
    }
    if (actT1){
      const u64* ab = hbu + (size_t)(isl0 ? 0 : (lgx-1))*8192;
      const u64* a0p = ab + (size_t)c*256 + w*64 + q*2;
      const u64* a1p = a0p + 16*256;
      const unsigned short* wp = wlds + 32896 + c*1032 + w*256 + q*8;
      matvec<8>(a0p, a1p, wp, z10, z11);
    }
    if (actT2 && w > 0){
      float* p = &red[0][w-1][lane][0];
      #pragma unroll
      for (int r = 0; r < 4; r++){ p[r] = z20[r]; p[4+r] = z21[r]; }
    }
    if (actT1 && w != 1){
      float* p = &red[1][(w == 0) ? 0 : (w-1)][lane][0];
      #pragma unroll
      for (int r = 0; r < 4; r++){ p[r] = z10[r]; p[4+r] = z11[r]; }
    }
    __syncthreads();
    if (w == 0 && actT2){
      #pragma unroll
      for (int s = 0; s < 3; s++){
        const float* p = &red[0][s][lane][0];
        #pragma unroll
        for (int r = 0; r < 4; r++){ z20[r] += p[r]; z21[r] += p[4+r]; }
      }
      const int kidx = (n2 + c) >> 2, sh = (c & 3)*16;
      #pragma unroll
      for (int mt = 0; mt < 2; mt++){
        float f[4];
        #pragma unroll
        for (int r = 0; r < 4; r++){
          float pre = (mt ? z21[r] : z20[r]) + biasT2;
          f[r] = 1.0f / (1.0f + __expf(-pre));
        }
        if (g2 == 0){
          u64* zp = zbu + ((size_t)lz*1024 + n2 + c)*16 + mt*8 + q*2;
          st64(zp, pk2f(f[0], f[1])); st64(zp + 1, pk2f(f[2], f[3]));
        } else {
          #pragma unroll
          for (int r = 0; r < 4; r++){
            int b = mt*16 + q*4 + r;
            u64 hw = ld64(hbu + (size_t)lz*8192 + (size_t)b*256 + kidx);
            rtA[c*33 + b] = f[r] * bf2f((unsigned short)(hw >> sh));
          }
        }
      }
    }
    if (w == 1 && actT1){
      #pragma unroll
      for (int s = 0; s < 3; s++){
        const float* p = &red[1][s][lane][0];
        #pragma unroll
        for (int r = 0; r < 4; r++){ z10[r] += p[r]; z11[r] += p[4+r]; }
      }
      if (isl0){
        const int kidx = (n1 + c) >> 2, sh = (c & 3)*16;
        const unsigned short* xr = xp + ((size_t)t1*H3 + g1*1024 + n1 + c)*32;
        #pragma unroll
        for (int mt = 0; mt < 2; mt++){
          us4 xv = *(const us4*)(xr + mt*16 + q*4);
          float f[4];
          #pragma unroll
          for (int r = 0; r < 4; r++){
            float pre = (mt ? z11[r] : z10[r]) + bf2f(xv[r]);
            f[r] = 1.0f / (1.0f + __expf(-pre));
          }
          if (g1 == 0){
            u64* zp = zbu + ((size_t)0 + n1 + c)*16 + mt*8 + q*2;
            st64(zp, pk2f(f[0], f[1])); st64(zp + 1, pk2f(f[2], f[3]));
          } else {
            #pragma unroll
            for (int r = 0; r < 4; r++){
              int b = mt*16 + q*4 + r;
              u64 hw = ld64(hbu + (size_t)b*256 + kidx);
              rtB[c*33 + b] = f[r] * bf2f((unsigned short)(hw >> sh));
            }
          }
        }
      } else {
        #pragma unroll
        for (int mt = 0; mt < 2; mt++){
          float f[4];
          #pragma unroll
          for (int r = 0; r < 4; r++) f[r] = (mt ? z11[r] : z10[r]) + biasGX;
          u64* gp = gxb + ((size_t)lgx*1024 + n1 + c)*16 + mt*8 + q*2;
          st64(gp, pk2f(f[0], f[1])); st64(gp + 1, pk2f(f[2], f[3]));
        }
      }
    }
    __syncthreads();
    if (g2 == 1 && actT2 && tid < 128){
      int b = tid & 31, p2 = tid >> 5;
      st64(rhbu + (size_t)lz*8192 + (size_t)b*256 + (n2 >> 2) + p2,
           pk4(rtA[(4*p2+0)*33+b], rtA[(4*p2+1)*33+b], rtA[(4*p2+2)*33+b], rtA[(4*p2+3)*33+b]));
    }
    if (isl0 && g1 == 1 && actT1 && tid >= 128){
      int tt = tid - 128; int b = tt & 31, p2 = tt >> 5;
      st64(rhbu + (size_t)b*256 + (n1 >> 2) + p2,
           pk4(rtB[(4*p2+0)*33+b], rtB[(4*p2+1)*33+b], rtB[(4*p2+2)*33+b], rtB[(4*p2+3)*33+b]));
    }
    gbar(flags, ep); ep++;

    // ================= phase B =================
    f32x4 gb0 = {0,0,0,0}, gb1 = {0,0,0,0};
    if (actB){
      const u64* ab = rhbu + (size_t)lb*8192;
      const u64* a0p = ab + (size_t)c*256 + w*64 + q*2;
      const u64* a1p = a0p + 16*256;
      const unsigned short* wp = wlds + 49408 + c*1032 + w*256 + q*8;
      matvec<8>(a0p, a1p, wp, gb0, gb1);
      if (w > 0){
        float* p = &red[0][w-1][lane][0];
        #pragma unroll
        for (int r = 0; r < 4; r++){ p[r] = gb0[r]; p[4+r] = gb1[r]; }
      }
    }
    __syncthreads();
    if (actB && w == 0){
      #pragma unroll
      for (int s = 0; s < 3; s++){
        const float* p = &red[0][s][lane][0];
        #pragma unroll
        for (int r = 0; r < 4; r++){ gb0[r] += p[r]; gb1[r] += p[4+r]; }
      }
      #pragma unroll
      for (int mt = 0; mt < 2; mt++){
        float gadd[4];
        if (lb == 0){
          us4 xv = *(const us4*)(xp + ((size_t)tb*H3 + 2048 + nb + c)*32 + mt*16 + q*4);
          #pragma unroll
          for (int r = 0; r < 4; r++) gadd[r] = bf2f(xv[r]);
        } else {
          const u64* gp = gxb + ((size_t)lb*1024 + nb + c)*16 + mt*8 + q*2;
          u64 u01 = ld64(gp), u23 = ld64(gp + 1);
          gadd[0] = lo32f(u01); gadd[1] = hi32f(u01); gadd[2] = lo32f(u23); gadd[3] = hi32f(u23);
        }
        const u64* zp = zbu + ((size_t)lb*1024 + nb + c)*16 + mt*8 + q*2;
        u64 z01 = ld64(zp), z23 = ld64(zp + 1);
        float zf[4] = { lo32f(z01), hi32f(z01), lo32f(z23), hi32f(z23) };
        float* hp = hrow + ((size_t)lb*1024 + nb + c)*32 + mt*16 + q*4;
        f32x4 h4 = *(const f32x4*)hp;
        f32x4 hn4;
        #pragma unroll
        for (int r = 0; r < 4; r++){
          float gpre = (mt ? gb1[r] : gb0[r]) + gadd[r];
          float gv = tanhf(gpre);
          float hnv = zf[r]*h4[r] + (1.0f - zf[r])*gv;
          hn4[r] = hnv;
          rtA[c*33 + mt*16 + q*4 + r] = hnv;
          if (tb == 511) outp[OUT_OFF + ((size_t)(mt*16 + q*4 + r)*3 + lb)*H_ + nb + c] = hnv;
        }
        *(f32x4*)hp = hn4;
      }
    }
    __syncthreads();
    if (actB && tid < 128){
      int b = tid & 31, p2 = tid >> 5;
      u64 pk = pk4(rtA[(4*p2+0)*33+b], rtA[(4*p2+1)*33+b], rtA[(4*p2+2)*33+b], rtA[(4*p2+3)*33+b]);
      st64(hbu + (size_t)lb*8192 + (size_t)b*256 + (nb >> 2) + p2, pk);
      if (lb == 2) *(u64*)(h2u + ((size_t)tb*32 + b)*256 + (nb >> 2) + p2) = pk;
    }
    gbar(flags, ep); ep++;
  }
}

extern "C" void kernel_launch(void* const* d_in, const int* in_sizes, int n_in,
                              void* d_out, int out_size, void* d_ws, size_t ws_size,
                              hipStream_t stream){
  (void)in_sizes; (void)n_in; (void)out_size;
  if (ws_size < WS_NEED) return;

  const float* x    = (const float*)d_in[0];
  const float* h0   = (const float*)d_in[1];
  const float* Wx0  = (const float*)d_in[2];
  const float* Wh0  = (const float*)d_in[3];
  const float* bh0  = (const float*)d_in[4];
  const float* Wx   = (const float*)d_in[5];
  const float* Wh   = (const float*)d_in[6];
  const float* bh   = (const float*)d_in[7];
  const float* Wout = (const float*)d_in[8];
  const float* bout = (const float*)d_in[9];
  float* out = (float*)d_out;

  char* ws = (char*)d_ws;
  unsigned short* xp    = (unsigned short*)(ws + XP_OFF);
  unsigned short* h2    = (unsigned short*)(ws + H2_OFF);
  unsigned short* xbf   = (unsigned short*)(ws + XBF_OFF);
  unsigned short* wx0b  = (unsigned short*)(ws + WX0B_OFF);
  unsigned short* wzr0  = (unsigned short*)(ws + WZR0_OFF);
  unsigned short* wg0   = (unsigned short*)(ws + WG0_OFF);
  unsigned short* wzr1  = (unsigned short*)(ws + WZR1_OFF);
  unsigned short* wgx1  = (unsigned short*)(ws + WGX1_OFF);
  unsigned short* wg1   = (unsigned short*)(ws + WG1_OFF);
  unsigned short* wzr2  = (unsigned short*)(ws + WZR2_OFF);
  unsigned short* wgx2  = (unsigned short*)(ws + WGX2_OFF);
  unsigned short* wg2   = (unsigned short*)(ws + WG2_OFF);
  unsigned short* woutb = (unsigned short*)(ws + WOUTB_OFF);

  hipMemsetAsync(ws + FLAG_OFF, 0, 4096, stream);

  // weight preparation
  k_conv<<<3072, 256, 0, stream>>>(Wx0, wx0b, 786432);
  k_conv<<<8192, 256, 0, stream>>>(Wh0, wzr0, 2097152);
  k_conv<<<4096, 256, 0, stream>>>(Wh0 + 2097152, wg0, 1048576);
  k_packzr<<<16384, 256, 0, stream>>>(Wh, Wx, wzr1);
  k_conv<<<4096, 256, 0, stream>>>(Wx + 2097152, wgx1, 1048576);
  k_conv<<<4096, 256, 0, stream>>>(Wh + 2097152, wg1, 1048576);
  k_packzr<<<16384, 256, 0, stream>>>(Wh + 3145728, Wx + 3145728, wzr2);
  k_conv<<<4096, 256, 0, stream>>>(Wx + 5242880, wgx2, 1048576);
  k_conv<<<4096, 256, 0, stream>>>(Wh + 5242880, wg2, 1048576);
  k_conv<<<1024, 256, 0, stream>>>(Wout, woutb, 262144);
  k_convx<<<16384, 256, 0, stream>>>(x, xbf);

  // layer-0 input projection (bias folded)
  {
    dim3 g(24, 128);
    k_gemm<<<g, 256, 0, stream>>>(xbf, wx0b, bh0, (void*)xp, 256, 0, H3);
  }
  // fused pipelined recurrence (all 3 layers), weights LDS-resident
  k_fused<<<256, 256, 0, stream>>>(ws, h0, bh, out);
  // output projection
  {
    dim3 g(2, 128);
    k_gemm<<<g, 256, 0, stream>>>(h2, woutb, bout, (void*)out, 1024, 1, 256);
  }
}

// Round 5
// 8967.276 us; speedup vs baseline: 4.9959x; 1.6634x over previous
//
#include <hip/hip_runtime.h>
#include <cstdint>
#include <cstddef>

#define S_  512
#define H_  1024
#define H3  3072
#define OUT_OFF 4194304  // B*S*O

typedef __attribute__((ext_vector_type(8))) short  short8;
typedef __attribute__((ext_vector_type(4))) float  f32x4;
typedef __attribute__((ext_vector_type(4))) unsigned short us4;
typedef __attribute__((ext_vector_type(4))) unsigned int   u32x4;
typedef unsigned long long u64;

#define MFMA __builtin_amdgcn_mfma_f32_16x16x32_bf16

// ---- workspace layout (bytes) ----
static const size_t XP_OFF    = 0;            // bf16 [512][3072][32]
static const size_t H2_OFF    = 100663296;    // bf16 [16384][1024]
static const size_t XBF_OFF   = 134217728;    // bf16 [16384][256]
static const size_t WX0B_OFF  = 142606336;
static const size_t WZR0_OFF  = 144179200;
static const size_t WG0_OFF   = 148373504;
static const size_t WZR1_OFF  = 150470656;
static const size_t WGX1_OFF  = 158859264;
static const size_t WG1_OFF   = 160956416;
static const size_t WZR2_OFF  = 163053568;
static const size_t WGX2_OFF  = 171442176;
static const size_t WG2_OFF   = 173539328;
static const size_t WOUTB_OFF = 175636480;
static const size_t ZBU_OFF   = 176160768;    // u64 [3][1024][16] fp32-pair z
static const size_t GXB_OFF   = 176553984;    // u64 [3][1024][16] fp32-pair gx
static const size_t HROW_OFF  = 176947200;    // f32 [3][1024][32] block-local h
static const size_t FLAG_OFF  = 177340416;    // 4096
static const size_t HH_OFF    = 177344512;    // hist h: u64 [515][3][256kc][32b]
static const size_t RHH_OFF   = 278597632;    // hist rh: u64 [514][3][256][32]
static const size_t WS_HIST   = 379654144;
static const size_t WS_BASE   = 177737728;    // HH used as single-slot h+rh

__device__ inline unsigned short f2bf(float f){
  unsigned u = __builtin_bit_cast(unsigned, f);
  unsigned r = u + 0x7fffu + ((u >> 16) & 1u);
  return (unsigned short)(r >> 16);
}
__device__ inline float bf2f(unsigned short s){
  unsigned u = ((unsigned)s) << 16;
  return __builtin_bit_cast(float, u);
}
__device__ inline unsigned ld_sys(const unsigned* p){
  return __hip_atomic_load(p, __ATOMIC_RELAXED, __HIP_MEMORY_SCOPE_SYSTEM);
}
__device__ inline void st_sys(unsigned* p, unsigned v){
  __hip_atomic_store(p, v, __ATOMIC_RELAXED, __HIP_MEMORY_SCOPE_SYSTEM);
}
__device__ inline u64 ld64(const u64* p){
  return __hip_atomic_load(p, __ATOMIC_RELAXED, __HIP_MEMORY_SCOPE_SYSTEM);
}
__device__ inline void st64(u64* p, u64 v){
  __hip_atomic_store(p, v, __ATOMIC_RELAXED, __HIP_MEMORY_SCOPE_SYSTEM);
}
template<bool HIST>
__device__ inline u64 LD(const u64* p){
  if constexpr (HIST) return *p; else return ld64(p);
}
__device__ inline short8 mk8u(u64 a, u64 b){
  u32x4 u; u.x = (unsigned)a; u.y = (unsigned)(a >> 32); u.z = (unsigned)b; u.w = (unsigned)(b >> 32);
  return __builtin_bit_cast(short8, u);
}
__device__ inline u64 pk4(float a, float b, float c, float d){
  return (u64)f2bf(a) | ((u64)f2bf(b) << 16) | ((u64)f2bf(c) << 32) | ((u64)f2bf(d) << 48);
}
__device__ inline u64 pk2f(float a, float b){
  return (u64)__builtin_bit_cast(unsigned, a) | ((u64)__builtin_bit_cast(unsigned, b) << 32);
}
__device__ inline float lo32f(u64 u){ return __builtin_bit_cast(float, (unsigned)u); }
__device__ inline float hi32f(u64 u){ return __builtin_bit_cast(float, (unsigned)(u >> 32)); }

// ---------------- prep kernels ----------------
__global__ void k_conv(const float* __restrict__ src, unsigned short* __restrict__ dst, int n){
  int i = blockIdx.x*256 + threadIdx.x;
  if (i < n) dst[i] = f2bf(src[i]);
}
__global__ void k_packzr(const float* __restrict__ Wh, const float* __restrict__ Wx,
                         unsigned short* __restrict__ dst){
  size_t i = (size_t)blockIdx.x*256 + threadIdx.x;
  int k = (int)(i & 2047);
  int n = (int)(i >> 11);
  float v = (k < 1024) ? Wh[(size_t)n*1024 + k] : Wx[(size_t)n*1024 + (k - 1024)];
  dst[i] = f2bf(v);
}
__global__ void k_convx(const float* __restrict__ x, unsigned short* __restrict__ xbf){
  int row = blockIdx.x;
  int s = row >> 5, b = row & 31;
  int i = threadIdx.x;
  xbf[(size_t)row*256 + i] = f2bf(x[((size_t)b*S_ + s)*256 + i]);
}

// ---------------- bf16 MFMA GEMM (proven) ----------------
__global__ __launch_bounds__(256) void k_gemm(const unsigned short* __restrict__ A,
                                              const unsigned short* __restrict__ Bw,
                                              const float* __restrict__ bias,
                                              void* __restrict__ Cout,
                                              int Kd, int mode, int Nd){
  __shared__ __align__(16) unsigned short lA[128*40];
  __shared__ __align__(16) unsigned short lB[128*40];
  int bm = blockIdx.y * 128, bn = blockIdx.x * 128;
  int tid = threadIdx.x;
  int w = tid >> 6, lane = tid & 63, q = lane >> 4, cc = lane & 15;
  int wm = (w >> 1) * 64, wn = (w & 1) * 64;
  f32x4 acc[4][4] = {};
  for (int k0 = 0; k0 < Kd; k0 += 32){
    #pragma unroll
    for (int i = 0; i < 2; i++){
      int idx = tid + i*256;
      int r = idx >> 2, ch = idx & 3;
      int m = bm + r;
      int arow = (mode == 0) ? m : ((m & 511)*32 + (m >> 9));
      *(u32x4*)(lA + r*40 + ch*8) = *(const u32x4*)(A + (size_t)arow*Kd + k0 + ch*8);
      *(u32x4*)(lB + r*40 + ch*8) = *(const u32x4*)(Bw + (size_t)(bn + r)*Kd + k0 + ch*8);
    }
    __syncthreads();
    short8 af[4], bfv[4];
    #pragma unroll
    for (int i = 0; i < 4; i++) af[i]  = *(const short8*)(lA + (wm + i*16 + cc)*40 + q*8);
    #pragma unroll
    for (int i = 0; i < 4; i++) bfv[i] = *(const short8*)(lB + (wn + i*16 + cc)*40 + q*8);
    #pragma unroll
    for (int i = 0; i < 4; i++)
      #pragma unroll
      for (int j = 0; j < 4; j++)
        acc[i][j] = MFMA(af[i], bfv[j], acc[i][j], 0, 0, 0);
    __syncthreads();
  }
  if (mode == 0){
    unsigned short* xp = (unsigned short*)Cout;
    #pragma unroll
    for (int i = 0; i < 4; i++){
      #pragma unroll
      for (int j = 0; j < 4; j++){
        int m = bm + wm + i*16 + q*4;
        int n = bn + wn + j*16 + cc;
        float bv = bias[n];
        int s = m >> 5, b0 = m & 31;
        us4 pk;
        #pragma unroll
        for (int reg = 0; reg < 4; reg++) pk[reg] = f2bf(acc[i][j][reg] + bv);
        *(us4*)(xp + ((size_t)s*H3 + n)*32 + b0) = pk;
      }
    }
  } else {
    float* C = (float*)Cout;
    #pragma unroll
    for (int i = 0; i < 4; i++){
      #pragma unroll
      for (int j = 0; j < 4; j++){
        int m = bm + wm + i*16 + q*4;
        int n = bn + wn + j*16 + cc;
        float bv = bias[n];
        #pragma unroll
        for (int reg = 0; reg < 4; reg++)
          C[(size_t)(m + reg)*Nd + n] = acc[i][j][reg] + bv;
      }
    }
  }
}

// ---------------- barrier ----------------
__device__ inline void gbar(unsigned* flags, unsigned ep){
  __syncthreads();
  if (threadIdx.x == 0) st_sys(flags + blockIdx.x, ep);
  if (threadIdx.x < 64){
    for (;;){
      unsigned v0 = ld_sys(flags + threadIdx.x);
      unsigned v1 = ld_sys(flags + 64 + threadIdx.x);
      unsigned v2 = ld_sys(flags + 128 + threadIdx.x);
      unsigned v3 = ld_sys(flags + 192 + threadIdx.x);
      if (__all((v0 >= ep) && (v1 >= ep) && (v2 >= ep) && (v3 >= ep))) break;
      __builtin_amdgcn_s_sleep(1);
    }
  }
  __syncthreads();
}

// matvec, k-major A layout [kc][b] (u64 chunks of 4 bf16).
// p0 = base + (kc0 + q*2)*32 + c ; per iter +256 (8 chunks). acc1 = b+16.
template<int NITER, bool HIST>
__device__ inline void matvec(const u64* p0, const unsigned short* wp,
                              f32x4& acc0, f32x4& acc1){
  u64 buf[2][4][4];
  #pragma unroll
  for (int ii = 0; ii < 4; ii++){
    const u64* p = p0 + ii*256;
    buf[0][ii][0] = LD<HIST>(p);      buf[0][ii][1] = LD<HIST>(p + 32);
    buf[0][ii][2] = LD<HIST>(p + 16); buf[0][ii][3] = LD<HIST>(p + 48);
  }
  constexpr int NCH = NITER / 4;
  #pragma unroll
  for (int ch = 0; ch < NCH; ch++){
    const int cur = ch & 1, nxt = cur ^ 1;
    if (ch + 1 < NCH){
      #pragma unroll
      for (int ii = 0; ii < 4; ii++){
        const u64* p = p0 + ((ch+1)*4 + ii)*256;
        buf[nxt][ii][0] = LD<HIST>(p);      buf[nxt][ii][1] = LD<HIST>(p + 32);
        buf[nxt][ii][2] = LD<HIST>(p + 16); buf[nxt][ii][3] = LD<HIST>(p + 48);
      }
    }
    #pragma unroll
    for (int ii = 0; ii < 4; ii++){
      short8 bw = *(const short8*)(wp + (ch*4 + ii)*32);
      acc0 = MFMA(mk8u(buf[cur][ii][0], buf[cur][ii][1]), bw, acc0, 0, 0, 0);
      acc1 = MFMA(mk8u(buf[cur][ii][2], buf[cur][ii][3]), bw, acc1, 0, 0, 0);
    }
  }
}

// ---------------- fused 3-layer pipelined persistent recurrence ----------------
template<bool HIST>
__global__ __launch_bounds__(256, 1) void k_fused(char* __restrict__ ws,
                                                  const float* __restrict__ h0,
                                                  const float* __restrict__ bh,
                                                  float* __restrict__ outp,
                                                  u64* __restrict__ hh,
                                                  u64* __restrict__ rhh){
  __shared__ __align__(16) unsigned short wlds[65920];
  __shared__ __align__(16) float red[2][3][64][10];
  __shared__ float rtA[16*33];
  __shared__ float rtB[16*33];

  const int tid = threadIdx.x;
  const int w = tid >> 6, lane = tid & 63, q = (lane >> 4) & 3, c = lane & 15;
  const int i = blockIdx.x;

  const int lz   = 1 + (i >> 7);
  const int g2   = (i >> 6) & 1;
  const int n2   = (i & 63) << 4;
  const bool isl0 = (i < 128);
  const int g1   = (i >> 6) & 1;
  const int lgx  = 1 + ((i >> 6) & 1);
  const int n1   = (i & 63) << 4;
  const bool hasB = (i < 192);
  const int lb   = i >> 6;
  const int nb   = (i & 63) << 4;

  const unsigned short* xp = (const unsigned short*)(ws + XP_OFF);
  u64* h2u   = (u64*)(ws + H2_OFF);
  u64* zbu   = (u64*)(ws + ZBU_OFF);
  u64* gxb   = (u64*)(ws + GXB_OFF);
  float* hrow = (float*)(ws + HROW_OFF);
  unsigned* flags = (unsigned*)(ws + FLAG_OFF);

  // ---- stage weights into LDS ----
  {
    const unsigned short* src2 = (const unsigned short*)(ws + (lz == 1 ? WZR1_OFF : WZR2_OFF))
                                 + (size_t)(g2*1024 + n2)*2048;
    for (int idx = tid; idx < 4096; idx += 256){
      int kc = idx & 255, row = idx >> 8;
      u32x4 v = *(const u32x4*)(src2 + (size_t)row*2048 + kc*8);
      *(u32x4*)(wlds + row*2056 + kc*8) = v;
    }
    const unsigned short* src1 = isl0
      ? (const unsigned short*)(ws + WZR0_OFF) + (size_t)(g1*1024 + n1)*1024
      : (const unsigned short*)(ws + (lgx == 1 ? WGX1_OFF : WGX2_OFF)) + (size_t)n1*1024;
    for (int idx = tid; idx < 2048; idx += 256){
      int kc = idx & 127, row = idx >> 7;
      u32x4 v = *(const u32x4*)(src1 + (size_t)row*1024 + kc*8);
      *(u32x4*)(wlds + 32896 + row*1032 + kc*8) = v;
    }
    if (hasB){
      const unsigned short* srcb = (const unsigned short*)(ws + (lb == 0 ? WG0_OFF : (lb == 1 ? WG1_OFF : WG2_OFF)))
                                   + (size_t)nb*1024;
      for (int idx = tid; idx < 2048; idx += 256){
        int kc = idx & 127, row = idx >> 7;
        u32x4 v = *(const u32x4*)(srcb + (size_t)row*1024 + kc*8);
        *(u32x4*)(wlds + 49408 + row*1032 + kc*8) = v;
      }
    }
  }
  const float biasT2 = bh[(size_t)(lz-1)*H3 + g2*1024 + n2 + c];
  const float biasGX = isl0 ? 0.f : bh[(size_t)(lgx-1)*H3 + 2048 + n1 + c];

  // ---- init h state ----
  if (hasB){
    for (int idx = tid; idx < 512; idx += 256){
      int n = idx >> 5, b = idx & 31;
      float v = h0[((size_t)b*3 + lb)*H_ + nb + n];
      hrow[((size_t)lb*1024 + nb + n)*32 + b] = v;
      rtA[n*33 + b] = v;
    }
  }
  __syncthreads();
  if (hasB && tid < 128){
    int b = tid & 31, p2 = tid >> 5;
    u64 pkv = pk4(rtA[(4*p2+0)*33+b], rtA[(4*p2+1)*33+b], rtA[(4*p2+2)*33+b], rtA[(4*p2+3)*33+b]);
    st64(hh + (size_t)(HIST ? lb : 0)*24576 + (size_t)lb*8192 + (size_t)((nb >> 2) + p2)*32 + b, pkv);
  }
  unsigned ep = 1;
  gbar(flags, ep); ep++;

  for (int T = 0; T < 514; T++){
    const int t2 = T - lz;
    const bool actT2 = (unsigned)t2 < 512u;
    const int t1 = isl0 ? T : (T - lgx);
    const bool actT1 = (unsigned)t1 < 512u;
    const int tb = T - lb;
    const bool actB = hasB && ((unsigned)tb < 512u);

    const u64* hslotR = hh + (size_t)(HIST ? T : 0)*24576;
    u64*       rslot  = rhh + (size_t)(HIST ? T : 0)*24576;

    // ================= phase A =================
    f32x4 z20 = {0,0,0,0}, z21 = {0,0,0,0};
    f32x4 z10 = {0,0,0,0}, z11 = {0,0,0,0};
    if (actT2){
      const u64* p0 = hslotR + (size_t)((w < 2) ? lz : (lz-1))*8192 + (size_t)((w & 1)*128 + q*2)*32 + c;
      const unsigned short* wp = wlds + c*2056 + w*512 + q*8;
      matvec<16, HIST>(p0, wp, z20, z21);
    }
    if (actT1){
      const u64* p0 = hslotR + (size_t)(isl0 ? 0 : (lgx-1))*8192 + (size_t)(w*64 + q*2)*32 + c;
      const unsigned short* wp = wlds + 32896 + c*1032 + w*256 + q*8;
      matvec<8, HIST>(p0, wp, z10, z11);
    }
    if (actT2 && w > 0){
      float* p = &red[0][w-1][lane][0];
      #pragma unroll
      for (int r = 0; r < 4; r++){ p[r] = z20[r]; p[4+r] = z21[r]; }
    }
    if (actT1 && w != 1){
      float* p = &red[1][(w == 0) ? 0 : (w-1)][lane][0];
      #pragma unroll
      for (int r = 0; r < 4; r++){ p[r] = z10[r]; p[4+r] = z11[r]; }
    }
    __syncthreads();
    if (w == 0 && actT2){
      #pragma unroll
      for (int s = 0; s < 3; s++){
        const float* p = &red[0][s][lane][0];
        #pragma unroll
        for (int r = 0; r < 4; r++){ z20[r] += p[r]; z21[r] += p[4+r]; }
      }
      const int kidx = (n2 + c) >> 2, sh = (c & 3)*16;
      const u64* hlz = hslotR + (size_t)lz*8192;
      #pragma unroll
      for (int mt = 0; mt < 2; mt++){
        float f[4];
        #pragma unroll
        for (int r = 0; r < 4; r++){
          float pre = (mt ? z21[r] : z20[r]) + biasT2;
          f[r] = 1.0f / (1.0f + __expf(-pre));
        }
        if (g2 == 0){
          u64* zp = zbu + ((size_t)lz*1024 + n2 + c)*16 + mt*8 + q*2;
          st64(zp, pk2f(f[0], f[1])); st64(zp + 1, pk2f(f[2], f[3]));
        } else {
          #pragma unroll
          for (int r = 0; r < 4; r++){
            int b = mt*16 + q*4 + r;
            u64 hw = LD<HIST>(hlz + (size_t)kidx*32 + b);
            rtA[c*33 + b] = f[r] * bf2f((unsigned short)(hw >> sh));
          }
        }
      }
    }
    if (w == 1 && actT1){
      #pragma unroll
      for (int s = 0; s < 3; s++){
        const float* p = &red[1][s][lane][0];
        #pragma unroll
        for (int r = 0; r < 4; r++){ z10[r] += p[r]; z11[r] += p[4+r]; }
      }
      if (isl0){
        const int kidx = (n1 + c) >> 2, sh = (c & 3)*16;
        const unsigned short* xr = xp + ((size_t)t1*H3 + g1*1024 + n1 + c)*32;
        #pragma unroll
        for (int mt = 0; mt < 2; mt++){
          us4 xv = *(const us4*)(xr + mt*16 + q*4);
          float f[4];
          #pragma unroll
          for (int r = 0; r < 4; r++){
            float pre = (mt ? z11[r] : z10[r]) + bf2f(xv[r]);
            f[r] = 1.0f / (1.0f + __expf(-pre));
          }
          if (g1 == 0){
            u64* zp = zbu + ((size_t)n1 + c)*16 + mt*8 + q*2;
            st64(zp, pk2f(f[0], f[1])); st64(zp + 1, pk2f(f[2], f[3]));
          } else {
            #pragma unroll
            for (int r = 0; r < 4; r++){
              int b = mt*16 + q*4 + r;
              u64 hw = LD<HIST>(hslotR + (size_t)kidx*32 + b);
              rtB[c*33 + b] = f[r] * bf2f((unsigned short)(hw >> sh));
            }
          }
        }
      } else {
        #pragma unroll
        for (int mt = 0; mt < 2; mt++){
          float f[4];
          #pragma unroll
          for (int r = 0; r < 4; r++) f[r] = (mt ? z11[r] : z10[r]) + biasGX;
          u64* gp = gxb + ((size_t)lgx*1024 + n1 + c)*16 + mt*8 + q*2;
          st64(gp, pk2f(f[0], f[1])); st64(gp + 1, pk2f(f[2], f[3]));
        }
      }
    }
    __syncthreads();
    if (g2 == 1 && actT2 && tid < 128){
      int b = tid & 31, p2 = tid >> 5;
      st64(rslot + (size_t)lz*8192 + (size_t)((n2 >> 2) + p2)*32 + b,
           pk4(rtA[(4*p2+0)*33+b], rtA[(4*p2+1)*33+b], rtA[(4*p2+2)*33+b], rtA[(4*p2+3)*33+b]));
    }
    if (isl0 && g1 == 1 && actT1 && tid >= 128){
      int tt = tid - 128; int b = tt & 31, p2 = tt >> 5;
      st64(rslot + (size_t)((n1 >> 2) + p2)*32 + b,
           pk4(rtB[(4*p2+0)*33+b], rtB[(4*p2+1)*33+b], rtB[(4*p2+2)*33+b], rtB[(4*p2+3)*33+b]));
    }
    gbar(flags, ep); ep++;

    // ================= phase B =================
    f32x4 gb0 = {0,0,0,0}, gb1 = {0,0,0,0};
    if (actB){
      const u64* p0 = (const u64*)rslot + (size_t)lb*8192 + (size_t)(w*64 + q*2)*32 + c;
      const unsigned short* wp = wlds + 49408 + c*1032 + w*256 + q*8;
      matvec<8, HIST>(p0, wp, gb0, gb1);
      if (w > 0){
        float* p = &red[0][w-1][lane][0];
        #pragma unroll
        for (int r = 0; r < 4; r++){ p[r] = gb0[r]; p[4+r] = gb1[r]; }
      }
    }
    __syncthreads();
    if (actB && w == 0){
      #pragma unroll
      for (int s = 0; s < 3; s++){
        const float* p = &red[0][s][lane][0];
        #pragma unroll
        for (int r = 0; r < 4; r++){ gb0[r] += p[r]; gb1[r] += p[4+r]; }
      }
      #pragma unroll
      for (int mt = 0; mt < 2; mt++){
        float gadd[4];
        if (lb == 0){
          us4 xv = *(const us4*)(xp + ((size_t)tb*H3 + 2048 + nb + c)*32 + mt*16 + q*4);
          #pragma unroll
          for (int r = 0; r < 4; r++) gadd[r] = bf2f(xv[r]);
        } else {
          const u64* gp = gxb + ((size_t)lb*1024 + nb + c)*16 + mt*8 + q*2;
          u64 u01 = ld64(gp), u23 = ld64(gp + 1);
          gadd[0] = lo32f(u01); gadd[1] = hi32f(u01); gadd[2] = lo32f(u23); gadd[3] = hi32f(u23);
        }
        const u64* zp = zbu + ((size_t)lb*1024 + nb + c)*16 + mt*8 + q*2;
        u64 z01 = ld64(zp), z23 = ld64(zp + 1);
        float zf[4] = { lo32f(z01), hi32f(z01), lo32f(z23), hi32f(z23) };
        float* hp = hrow + ((size_t)lb*1024 + nb + c)*32 + mt*16 + q*4;
        f32x4 h4 = *(const f32x4*)hp;
        f32x4 hn4;
        #pragma unroll
        for (int r = 0; r < 4; r++){
          float gpre = (mt ? gb1[r] : gb0[r]) + gadd[r];
          float gv = tanhf(gpre);
          float hnv = zf[r]*h4[r] + (1.0f - zf[r])*gv;
          hn4[r] = hnv;
          rtA[c*33 + mt*16 + q*4 + r] = hnv;
          if (tb == 511) outp[OUT_OFF + ((size_t)(mt*16 + q*4 + r)*3 + lb)*H_ + nb + c] = hnv;
        }
        *(f32x4*)hp = hn4;
      }
    }
    __syncthreads();
    if (actB && tid < 128){
      int b = tid & 31, p2 = tid >> 5;
      u64 pkv = pk4(rtA[(4*p2+0)*33+b], rtA[(4*p2+1)*33+b], rtA[(4*p2+2)*33+b], rtA[(4*p2+3)*33+b]);
      st64(hh + (size_t)(HIST ? (T + 1) : 0)*24576 + (size_t)lb*8192 + (size_t)((nb >> 2) + p2)*32 + b, pkv);
      if (lb == 2) *(u64*)(h2u + ((size_t)tb*32 + b)*256 + (nb >> 2) + p2) = pkv;
    }
    gbar(flags, ep); ep++;
  }
}

extern "C" void kernel_launch(void* const* d_in, const int* in_sizes, int n_in,
                              void* d_out, int out_size, void* d_ws, size_t ws_size,
                              hipStream_t stream){
  (void)in_sizes; (void)n_in; (void)out_size;
  if (ws_size < WS_BASE) return;
  const bool hist = (ws_size >= WS_HIST);

  const float* x    = (const float*)d_in[0];
  const float* h0   = (const float*)d_in[1];
  const float* Wx0  = (const float*)d_in[2];
  const float* Wh0  = (const float*)d_in[3];
  const float* bh0  = (const float*)d_in[4];
  const float* Wx   = (const float*)d_in[5];
  const float* Wh   = (const float*)d_in[6];
  const float* bh   = (const float*)d_in[7];
  const float* Wout = (const float*)d_in[8];
  const float* bout = (const float*)d_in[9];
  float* out = (float*)d_out;

  char* ws = (char*)d_ws;
  unsigned short* xp    = (unsigned short*)(ws + XP_OFF);
  unsigned short* h2    = (unsigned short*)(ws + H2_OFF);
  unsigned short* xbf   = (unsigned short*)(ws + XBF_OFF);
  unsigned short* wx0b  = (unsigned short*)(ws + WX0B_OFF);
  unsigned short* wzr0  = (unsigned short*)(ws + WZR0_OFF);
  unsigned short* wg0   = (unsigned short*)(ws + WG0_OFF);
  unsigned short* wzr1  = (unsigned short*)(ws + WZR1_OFF);
  unsigned short* wgx1  = (unsigned short*)(ws + WGX1_OFF);
  unsigned short* wg1   = (unsigned short*)(ws + WG1_OFF);
  unsigned short* wzr2  = (unsigned short*)(ws + WZR2_OFF);
  unsigned short* wgx2  = (unsigned short*)(ws + WGX2_OFF);
  unsigned short* wg2   = (unsigned short*)(ws + WG2_OFF);
  unsigned short* woutb = (unsigned short*)(ws + WOUTB_OFF);
  u64* hh  = (u64*)(ws + HH_OFF);
  u64* rhh = hist ? (u64*)(ws + RHH_OFF) : (hh + 24576);

  hipMemsetAsync(ws + FLAG_OFF, 0, 4096, stream);

  k_conv<<<3072, 256, 0, stream>>>(Wx0, wx0b, 786432);
  k_conv<<<8192, 256, 0, stream>>>(Wh0, wzr0, 2097152);
  k_conv<<<4096, 256, 0, stream>>>(Wh0 + 2097152, wg0, 1048576);
  k_packzr<<<16384, 256, 0, stream>>>(Wh, Wx, wzr1);
  k_conv<<<4096, 256, 0, stream>>>(Wx + 2097152, wgx1, 1048576);
  k_conv<<<4096, 256, 0, stream>>>(Wh + 2097152, wg1, 1048576);
  k_packzr<<<16384, 256, 0, stream>>>(Wh + 3145728, Wx + 3145728, wzr2);
  k_conv<<<4096, 256, 0, stream>>>(Wx + 5242880, wgx2, 1048576);
  k_conv<<<4096, 256, 0, stream>>>(Wh + 5242880, wg2, 1048576);
  k_conv<<<1024, 256, 0, stream>>>(Wout, woutb, 262144);
  k_convx<<<16384, 256, 0, stream>>>(x, xbf);

  {
    dim3 g(24, 128);
    k_gemm<<<g, 256, 0, stream>>>(xbf, wx0b, bh0, (void*)xp, 256, 0, H3);
  }
  if (hist) k_fused<true ><<<256, 256, 0, stream>>>(ws, h0, bh, out, hh, rhh);
  else      k_fused<false><<<256, 256, 0, stream>>>(ws, h0, bh, out, hh, rhh);
  {
    dim3 g(2, 128);
    k_gemm<<<g, 256, 0, stream>>>(h2, woutb, bout, (void*)out, 1024, 1, 256);
  }
}